// Round 1
// baseline (981.407 us; speedup 1.0000x reference)
//
#include <hip/hip_runtime.h>
#include <hip/hip_bf16.h>
#include <math.h>

typedef __attribute__((ext_vector_type(8))) short short8;
typedef __attribute__((ext_vector_type(4))) float f32x4;
typedef __attribute__((ext_vector_type(4))) unsigned short u16x4;
typedef __attribute__((ext_vector_type(8))) unsigned short u16x8;
typedef unsigned short u16;

#define DM 2048
#define SQ 2048
#define NB 4
#define NH 16
#define DKH 128

__device__ __forceinline__ u16 f2bf(float f) {
  unsigned u = __float_as_uint(f);
  u += 0x7fffu + ((u >> 16) & 1u);
  return (u16)(u >> 16);
}

__device__ __forceinline__ void gload16(const u16* g, u16* lds) {
  __builtin_amdgcn_global_load_lds(
      (const __attribute__((address_space(1))) unsigned int*)g,
      (__attribute__((address_space(3))) unsigned int*)lds, 16, 0, 0);
}

__global__ void cvt_bf16(const float* __restrict__ in, u16* __restrict__ out, int n) {
  int i = (blockIdx.x * blockDim.x + threadIdx.x) * 4;
  if (i >= n) return;
  float4 v = *(const float4*)(in + i);
  u16x4 o;
  o.x = f2bf(v.x); o.y = f2bf(v.y); o.z = f2bf(v.z); o.w = f2bf(v.w);
  *(u16x4*)(out + i) = o;
}

// C = A @ B^T + bias.  A: [M][K] bf16, B: [N][K] bf16 (row-major weight), bias: [N] f32.
// 128x128 tile, BK=32, 4 waves each 64x64 (4x4 frags of 16x16x32 bf16 MFMA).
template <bool OUTF32>
__global__ __launch_bounds__(256) void gemm_bt(
    const u16* __restrict__ A, const u16* __restrict__ B,
    const float* __restrict__ bias, void* __restrict__ Cout,
    int M, int N, int K) {
  __shared__ u16 smA[128 * 32];
  __shared__ u16 smB[128 * 32];
  const int tid = threadIdx.x;
  const int w = tid >> 6, l = tid & 63;
  const int g = l >> 4, c = l & 15;
  const int m0 = blockIdx.y * 128, n0 = blockIdx.x * 128;
  const int wr = w >> 1, wc = w & 1;

  f32x4 acc[4][4] = {};

  const int srow = w * 32 + (l >> 2);   // staging row within tile
  const int scol = (l & 3) * 8;         // staging col (elements)
  const u16* Abase = A + (size_t)(m0 + srow) * K + scol;
  const u16* Bbase = B + (size_t)(n0 + srow) * K + scol;
  u16* ldsA = &smA[(w * 32) * 32];
  u16* ldsB = &smB[(w * 32) * 32];

  for (int kt = 0; kt < K; kt += 32) {
    __syncthreads();
    gload16(Abase + kt, ldsA);
    gload16(Abase + (size_t)16 * K + kt, ldsA + 16 * 32);
    gload16(Bbase + kt, ldsB);
    gload16(Bbase + (size_t)16 * K + kt, ldsB + 16 * 32);
    __syncthreads();
    short8 a[4], b[4];
#pragma unroll
    for (int mi = 0; mi < 4; ++mi)
      a[mi] = *(const short8*)&smA[(wr * 64 + mi * 16 + c) * 32 + g * 8];
#pragma unroll
    for (int ni = 0; ni < 4; ++ni)
      b[ni] = *(const short8*)&smB[(wc * 64 + ni * 16 + c) * 32 + g * 8];
#pragma unroll
    for (int mi = 0; mi < 4; ++mi)
#pragma unroll
      for (int ni = 0; ni < 4; ++ni)
        acc[mi][ni] = __builtin_amdgcn_mfma_f32_16x16x32_bf16(a[mi], b[ni], acc[mi][ni], 0, 0, 0);
  }

#pragma unroll
  for (int mi = 0; mi < 4; ++mi)
#pragma unroll
    for (int ni = 0; ni < 4; ++ni) {
      const int col = n0 + wc * 64 + ni * 16 + c;
      const float bv = bias[col];
#pragma unroll
      for (int rr = 0; rr < 4; ++rr) {
        const int row = m0 + wr * 64 + mi * 16 + g * 4 + rr;
        const float v = acc[mi][ni][rr] + bv;
        if (OUTF32)
          ((float*)Cout)[(size_t)row * N + col] = v;
        else
          ((u16*)Cout)[(size_t)row * N + col] = f2bf(v);
      }
    }
}

// Flash attention. Q,K,V: [NB*SQ][DM] bf16 (head h at cols h*128..h*128+128).
// Block: (qtile, h, b); 128 q-rows per block, 32 per wave; KV tiles of 64.
__global__ __launch_bounds__(256) void attn(
    const u16* __restrict__ Q, const u16* __restrict__ K,
    const u16* __restrict__ V, u16* __restrict__ O) {
  __shared__ u16 smK[4 * 64 * 32];    // [kk][kv][d32]  (d chunked by 32)
  __shared__ u16 smVt[2 * 128 * 32];  // [ks][d][kv32]  (kv chunked by 32, transposed)
  __shared__ u16 smP[4][32 * 72];     // per-wave P tile, padded rows (72 elems = 144B)
  const int tid = threadIdx.x;
  const int w = tid >> 6, l = tid & 63;
  const int g = l >> 4, c = l & 15;
  const int h = blockIdx.y, b = blockIdx.z;
  const int q0 = blockIdx.x * 128;
  const size_t rowb = (size_t)b * SQ;
  const int hoff = h * DKH;
  const float sc2 = 0.08838834764831845f * 1.4426950408889634f;  // 1/sqrt(128)*log2(e)

  short8 qf[2][4];
#pragma unroll
  for (int mi = 0; mi < 2; ++mi)
#pragma unroll
    for (int kk = 0; kk < 4; ++kk)
      qf[mi][kk] = *(const short8*)&Q[(rowb + q0 + w * 32 + mi * 16 + c) * DM + hoff + kk * 32 + g * 8];

  f32x4 o[2][8] = {};
  float mrow[2][4], lrow[2][4];
#pragma unroll
  for (int mi = 0; mi < 2; ++mi)
#pragma unroll
    for (int rr = 0; rr < 4; ++rr) { mrow[mi][rr] = -1e30f; lrow[mi][rr] = 0.f; }

  const int vkv = (tid & 31) * 2;  // even kv row handled by this thread
  const int vdg = tid >> 5;        // 0..7 -> d block of 16
  const int vck = vkv >> 5;        // kv chunk (0/1)
  const int vkc = vkv & 31;

  for (int kv0 = 0; kv0 < SQ; kv0 += 64) {
    __syncthreads();
    // ---- stage K (chunked linear, via global_load_lds) ----
#pragma unroll
    for (int kk = 0; kk < 4; ++kk)
      gload16(&K[(rowb + kv0 + w * 16 + (l >> 2)) * DM + hoff + kk * 32 + (l & 3) * 8],
              &smK[kk * 2048 + (w * 16) * 32]);
    // ---- stage V transposed ----
    {
      const u16* vp0 = &V[(rowb + kv0 + vkv) * DM + hoff + vdg * 16];
      const u16* vp1 = vp0 + DM;
      u16x8 a0 = *(const u16x8*)vp0;
      u16x8 a1 = *(const u16x8*)(vp0 + 8);
      u16x8 b0 = *(const u16x8*)vp1;
      u16x8 b1 = *(const u16x8*)(vp1 + 8);
#pragma unroll
      for (int i = 0; i < 8; ++i) {
        const int d = vdg * 16 + i;
        *(unsigned int*)&smVt[vck * 4096 + d * 32 + vkc] =
            (unsigned)a0[i] | ((unsigned)b0[i] << 16);
      }
#pragma unroll
      for (int i = 0; i < 8; ++i) {
        const int d = vdg * 16 + 8 + i;
        *(unsigned int*)&smVt[vck * 4096 + d * 32 + vkc] =
            (unsigned)a1[i] | ((unsigned)b1[i] << 16);
      }
    }
    __syncthreads();

    // ---- S = Q K^T (scaled later) ----
    f32x4 s[2][4] = {};
#pragma unroll
    for (int kk = 0; kk < 4; ++kk) {
      short8 kf[4];
#pragma unroll
      for (int ni = 0; ni < 4; ++ni)
        kf[ni] = *(const short8*)&smK[kk * 2048 + (ni * 16 + c) * 32 + g * 8];
#pragma unroll
      for (int mi = 0; mi < 2; ++mi)
#pragma unroll
        for (int ni = 0; ni < 4; ++ni)
          s[mi][ni] = __builtin_amdgcn_mfma_f32_16x16x32_bf16(qf[mi][kk], kf[ni], s[mi][ni], 0, 0, 0);
    }

    // ---- online softmax (exp2 domain) + write P to LDS ----
#pragma unroll
    for (int mi = 0; mi < 2; ++mi) {
      float ml[4];
#pragma unroll
      for (int rr = 0; rr < 4; ++rr) ml[rr] = -1e30f;
#pragma unroll
      for (int ni = 0; ni < 4; ++ni)
#pragma unroll
        for (int rr = 0; rr < 4; ++rr) {
          const float t = s[mi][ni][rr] * sc2;
          s[mi][ni][rr] = t;
          ml[rr] = fmaxf(ml[rr], t);
        }
#pragma unroll
      for (int off = 8; off >= 1; off >>= 1)
#pragma unroll
        for (int rr = 0; rr < 4; ++rr)
          ml[rr] = fmaxf(ml[rr], __shfl_xor(ml[rr], off));
      float al[4], rs[4];
#pragma unroll
      for (int rr = 0; rr < 4; ++rr) {
        const float mn = fmaxf(mrow[mi][rr], ml[rr]);
        al[rr] = exp2f(mrow[mi][rr] - mn);
        mrow[mi][rr] = mn;
        rs[rr] = 0.f;
      }
#pragma unroll
      for (int ni = 0; ni < 4; ++ni)
#pragma unroll
        for (int rr = 0; rr < 4; ++rr) {
          const float pv = exp2f(s[mi][ni][rr] - mrow[mi][rr]);
          rs[rr] += pv;
          smP[w][(mi * 16 + g * 4 + rr) * 72 + ni * 16 + c] = f2bf(pv);
        }
#pragma unroll
      for (int off = 8; off >= 1; off >>= 1)
#pragma unroll
        for (int rr = 0; rr < 4; ++rr)
          rs[rr] += __shfl_xor(rs[rr], off);
#pragma unroll
      for (int rr = 0; rr < 4; ++rr)
        lrow[mi][rr] = lrow[mi][rr] * al[rr] + rs[rr];
#pragma unroll
      for (int di = 0; di < 8; ++di)
#pragma unroll
        for (int rr = 0; rr < 4; ++rr)
          o[mi][di][rr] *= al[rr];
    }

    // ---- O += P V ----
#pragma unroll
    for (int ks = 0; ks < 2; ++ks) {
      short8 pa[2];
#pragma unroll
      for (int mi = 0; mi < 2; ++mi)
        pa[mi] = *(const short8*)&smP[w][(mi * 16 + c) * 72 + ks * 32 + g * 8];
#pragma unroll
      for (int di = 0; di < 8; ++di) {
        const short8 vb = *(const short8*)&smVt[ks * 4096 + (di * 16 + c) * 32 + g * 8];
#pragma unroll
        for (int mi = 0; mi < 2; ++mi)
          o[mi][di] = __builtin_amdgcn_mfma_f32_16x16x32_bf16(pa[mi], vb, o[mi][di], 0, 0, 0);
      }
    }
  }

  // ---- finalize: divide by l, store bf16 ----
#pragma unroll
  for (int mi = 0; mi < 2; ++mi) {
    float inv[4];
#pragma unroll
    for (int rr = 0; rr < 4; ++rr) inv[rr] = 1.0f / lrow[mi][rr];
#pragma unroll
    for (int di = 0; di < 8; ++di)
#pragma unroll
      for (int rr = 0; rr < 4; ++rr)
        O[(rowb + q0 + w * 32 + mi * 16 + g * 4 + rr) * DM + hoff + di * 16 + c] =
            f2bf(o[mi][di][rr] * inv[rr]);
  }
}

extern "C" void kernel_launch(void* const* d_in, const int* in_sizes, int n_in,
                              void* d_out, int out_size, void* d_ws, size_t ws_size,
                              hipStream_t stream) {
  const float* x    = (const float*)d_in[0];
  const float* wq_w = (const float*)d_in[1];
  const float* wq_b = (const float*)d_in[2];
  const float* wk_w = (const float*)d_in[3];
  const float* wk_b = (const float*)d_in[4];
  const float* wv_w = (const float*)d_in[5];
  const float* wv_b = (const float*)d_in[6];
  const float* wo_w = (const float*)d_in[7];
  const float* wo_b = (const float*)d_in[8];
  float* out = (float*)d_out;

  u16* p = (u16*)d_ws;
  u16* xb  = p; p += (size_t)NB * SQ * DM;
  u16* wqb = p; p += (size_t)DM * DM;
  u16* wkb = p; p += (size_t)DM * DM;
  u16* wvb = p; p += (size_t)DM * DM;
  u16* wob = p; p += (size_t)DM * DM;
  u16* Qb  = p; p += (size_t)NB * SQ * DM;
  u16* Kb  = p; p += (size_t)NB * SQ * DM;
  u16* Vb  = p; p += (size_t)NB * SQ * DM;
  u16* ctx = xb;  // reuse: x no longer needed after V projection

  const int nx = NB * SQ * DM;  // 16,777,216
  const int nw = DM * DM;       // 4,194,304
  cvt_bf16<<<dim3(nx / 1024), dim3(256), 0, stream>>>(x, xb, nx);
  cvt_bf16<<<dim3(nw / 1024), dim3(256), 0, stream>>>(wq_w, wqb, nw);
  cvt_bf16<<<dim3(nw / 1024), dim3(256), 0, stream>>>(wk_w, wkb, nw);
  cvt_bf16<<<dim3(nw / 1024), dim3(256), 0, stream>>>(wv_w, wvb, nw);
  cvt_bf16<<<dim3(nw / 1024), dim3(256), 0, stream>>>(wo_w, wob, nw);

  dim3 gg(DM / 128, (NB * SQ) / 128);
  gemm_bt<false><<<gg, dim3(256), 0, stream>>>(xb, wqb, wq_b, Qb, NB * SQ, DM, DM);
  gemm_bt<false><<<gg, dim3(256), 0, stream>>>(xb, wkb, wk_b, Kb, NB * SQ, DM, DM);
  gemm_bt<false><<<gg, dim3(256), 0, stream>>>(xb, wvb, wv_b, Vb, NB * SQ, DM, DM);

  attn<<<dim3(SQ / 128, NH, NB), dim3(256), 0, stream>>>(Qb, Kb, Vb, ctx);

  gemm_bt<true><<<gg, dim3(256), 0, stream>>>(ctx, wob, wo_b, out, NB * SQ, DM, DM);
}

// Round 2
// 788.722 us; speedup vs baseline: 1.2443x; 1.2443x over previous
//
#include <hip/hip_runtime.h>
#include <hip/hip_bf16.h>
#include <math.h>

typedef __attribute__((ext_vector_type(8))) short short8;
typedef __attribute__((ext_vector_type(4))) float f32x4;
typedef __attribute__((ext_vector_type(4))) unsigned short u16x4;
typedef __attribute__((ext_vector_type(8))) unsigned short u16x8;
typedef unsigned short u16;
typedef unsigned int u32;

#define DM 2048
#define SQ 2048
#define NB 4
#define NH 16
#define DKH 128
#define KT 64
#define NT (SQ / KT)

__device__ __forceinline__ u16 f2bf(float f) {
  unsigned u = __float_as_uint(f);
  u += 0x7fffu + ((u >> 16) & 1u);
  return (u16)(u >> 16);
}

__device__ __forceinline__ void gload16(const u16* g, u16* lds) {
  __builtin_amdgcn_global_load_lds(
      (const __attribute__((address_space(1))) unsigned int*)g,
      (__attribute__((address_space(3))) unsigned int*)lds, 16, 0, 0);
}

__global__ void cvt_bf16(const float* __restrict__ in, u16* __restrict__ out, int n) {
  int i = (blockIdx.x * blockDim.x + threadIdx.x) * 4;
  if (i >= n) return;
  float4 v = *(const float4*)(in + i);
  u16x4 o;
  o.x = f2bf(v.x); o.y = f2bf(v.y); o.z = f2bf(v.z); o.w = f2bf(v.w);
  *(u16x4*)(out + i) = o;
}

// C = (A @ B^T + bias) * oscale.  A: [M][K] bf16, B: [N][K] bf16, bias: [N] f32.
template <bool OUTF32>
__global__ __launch_bounds__(256) void gemm_bt(
    const u16* __restrict__ A, const u16* __restrict__ B,
    const float* __restrict__ bias, void* __restrict__ Cout,
    int M, int N, int K, float oscale) {
  __shared__ u16 smA[128 * 32];
  __shared__ u16 smB[128 * 32];
  const int tid = threadIdx.x;
  const int w = tid >> 6, l = tid & 63;
  const int g = l >> 4, c = l & 15;
  const int m0 = blockIdx.y * 128, n0 = blockIdx.x * 128;
  const int wr = w >> 1, wc = w & 1;

  f32x4 acc[4][4] = {};

  const int srow = w * 32 + (l >> 2);
  const int scol = (l & 3) * 8;
  const u16* Abase = A + (size_t)(m0 + srow) * K + scol;
  const u16* Bbase = B + (size_t)(n0 + srow) * K + scol;
  u16* ldsA = &smA[(w * 32) * 32];
  u16* ldsB = &smB[(w * 32) * 32];

  for (int kt = 0; kt < K; kt += 32) {
    __syncthreads();
    gload16(Abase + kt, ldsA);
    gload16(Abase + (size_t)16 * K + kt, ldsA + 16 * 32);
    gload16(Bbase + kt, ldsB);
    gload16(Bbase + (size_t)16 * K + kt, ldsB + 16 * 32);
    __syncthreads();
    short8 a[4], b[4];
#pragma unroll
    for (int mi = 0; mi < 4; ++mi)
      a[mi] = *(const short8*)&smA[(wr * 64 + mi * 16 + c) * 32 + g * 8];
#pragma unroll
    for (int ni = 0; ni < 4; ++ni)
      b[ni] = *(const short8*)&smB[(wc * 64 + ni * 16 + c) * 32 + g * 8];
#pragma unroll
    for (int mi = 0; mi < 4; ++mi)
#pragma unroll
      for (int ni = 0; ni < 4; ++ni)
        acc[mi][ni] = __builtin_amdgcn_mfma_f32_16x16x32_bf16(a[mi], b[ni], acc[mi][ni], 0, 0, 0);
  }

#pragma unroll
  for (int mi = 0; mi < 4; ++mi)
#pragma unroll
    for (int ni = 0; ni < 4; ++ni) {
      const int col = n0 + wc * 64 + ni * 16 + c;
      const float bv = bias[col];
#pragma unroll
      for (int rr = 0; rr < 4; ++rr) {
        const int row = m0 + wr * 64 + mi * 16 + g * 4 + rr;
        const float v = (acc[mi][ni][rr] + bv) * oscale;
        if (OUTF32)
          ((float*)Cout)[(size_t)row * N + col] = v;
        else
          ((u16*)Cout)[(size_t)row * N + col] = f2bf(v);
      }
    }
}

// Flash attention, 8 waves x 32 q-rows = 256 q-rows/block, KV tiles of 64,
// double-buffered K/V staging, XOR-swizzled LDS (conflict-free reads+writes),
// deferred-max online softmax (scale pre-folded into Q in log2 domain).
__global__ __launch_bounds__(512, 2) void attn(
    const u16* __restrict__ Q, const u16* __restrict__ K,
    const u16* __restrict__ V, u16* __restrict__ O) {
  // K: [buf][khalf(2)][kv(64)][64 d-elems], 128B rows, slot^=(kv&7)
  __shared__ u16 smK[2 * 8192];
  // V^T: [buf][d(128)][kv(64)], 128B rows, slot^=(d&7)
  __shared__ u16 smV[2 * 8192];
  // P: [wave][qrow(32)][kv(64)], 128B rows, slot^=(row&7)
  __shared__ u16 smP[8 * 2048];

  const int tid = threadIdx.x;
  const int w = tid >> 6, l = tid & 63;
  const int c = l & 15, g = l >> 4;
  const int h = blockIdx.y, b = blockIdx.z;
  const int q0 = blockIdx.x * 256;
  const size_t rowb = (size_t)b * SQ;
  const int hoff = h * DKH;

  // ---- Q fragments (rows w*32 + mi*16 + c), already scaled by 1/sqrt(dk)*log2e
  short8 qf[2][4];
#pragma unroll
  for (int mi = 0; mi < 2; ++mi)
#pragma unroll
    for (int kk = 0; kk < 4; ++kk)
      qf[mi][kk] = *(const short8*)&Q[(rowb + q0 + w * 32 + mi * 16 + c) * DM + hoff + kk * 32 + g * 8];

  f32x4 o[2][8] = {};
  float mrow[2][4], lrow[2][4];
#pragma unroll
  for (int mi = 0; mi < 2; ++mi)
#pragma unroll
    for (int rr = 0; rr < 4; ++rr) { mrow[mi][rr] = -1e30f; lrow[mi][rr] = 0.f; }

  // staging ids
  const int vdg = tid >> 5;        // 0..15: d-block of 8
  const int kvp = (tid & 31) * 2;  // kv pair base
  const int kq = w * 2;            // K-stage chunk base (2 per wave)
  const int k_kh0 = kq >> 3, k_kv0 = (kq & 7) * 8 + (l >> 3);
  const int k_kh1 = (kq + 1) >> 3, k_kv1 = ((kq + 1) & 7) * 8 + (l >> 3);
  const int k_sl = ((l & 7) ^ (l >> 3)) * 8;  // pre-swizzled global col (u16)

  u16x8 va, vb2;

  // ---- prologue: stage tile 0 into buf 0
  {
    const u16* vp = &V[(rowb + kvp) * DM + hoff + vdg * 8];
    va = *(const u16x8*)vp;
    vb2 = *(const u16x8*)(vp + DM);
    gload16(&K[(rowb + k_kv0) * DM + hoff + k_kh0 * 64 + k_sl], &smK[kq * 512]);
    gload16(&K[(rowb + k_kv1) * DM + hoff + k_kh1 * 64 + k_sl], &smK[(kq + 1) * 512]);
#pragma unroll
    for (int i = 0; i < 8; ++i) {
      const int d = vdg * 8 + i;
      const int slot = (kvp >> 3) ^ (d & 7);
      *(u32*)&smV[d * 64 + slot * 8 + (kvp & 7)] = (u32)va[i] | ((u32)vb2[i] << 16);
    }
  }
  __syncthreads();

  int buf = 0;
  for (int t = 0; t < NT; ++t) {
    const int nb = buf ^ 1;
    // ---- prefetch tile t+1 (issue-early)
    if (t + 1 < NT) {
      const size_t kvr = rowb + (size_t)(t + 1) * KT;
      const u16* vp = &V[(kvr + kvp) * DM + hoff + vdg * 8];
      va = *(const u16x8*)vp;
      vb2 = *(const u16x8*)(vp + DM);
      gload16(&K[(kvr + k_kv0) * DM + hoff + k_kh0 * 64 + k_sl], &smK[nb * 8192 + kq * 512]);
      gload16(&K[(kvr + k_kv1) * DM + hoff + k_kh1 * 64 + k_sl], &smK[nb * 8192 + (kq + 1) * 512]);
    }

    // ---- S = Q K^T (log2 domain)
    f32x4 s[2][4] = {};
#pragma unroll
    for (int kk = 0; kk < 4; ++kk) {
      const int kh = kk >> 1;
      const int slb = (kk & 1) * 4 + g;
      short8 kf[4];
#pragma unroll
      for (int ni = 0; ni < 4; ++ni)
        kf[ni] = *(const short8*)&smK[buf * 8192 + kh * 4096 + (ni * 16 + c) * 64 + (slb ^ (c & 7)) * 8];
#pragma unroll
      for (int mi = 0; mi < 2; ++mi)
#pragma unroll
        for (int ni = 0; ni < 4; ++ni)
          s[mi][ni] = __builtin_amdgcn_mfma_f32_16x16x32_bf16(qf[mi][kk], kf[ni], s[mi][ni], 0, 0, 0);
    }

    // ---- online softmax with deferred max
#pragma unroll
    for (int mi = 0; mi < 2; ++mi) {
      float ml[4];
#pragma unroll
      for (int rr = 0; rr < 4; ++rr)
        ml[rr] = fmaxf(fmaxf(s[mi][0][rr], s[mi][1][rr]), fmaxf(s[mi][2][rr], s[mi][3][rr]));
#pragma unroll
      for (int off = 8; off >= 1; off >>= 1)
#pragma unroll
        for (int rr = 0; rr < 4; ++rr)
          ml[rr] = fmaxf(ml[rr], __shfl_xor(ml[rr], off));
      int need = 0;
#pragma unroll
      for (int rr = 0; rr < 4; ++rr) need |= (ml[rr] > mrow[mi][rr] + 10.0f) ? 1 : 0;
      if (__any(need)) {
#pragma unroll
        for (int rr = 0; rr < 4; ++rr) {
          const float mn = fmaxf(mrow[mi][rr], ml[rr]);
          const float al = exp2f(mrow[mi][rr] - mn);
          mrow[mi][rr] = mn;
          lrow[mi][rr] *= al;
#pragma unroll
          for (int di = 0; di < 8; ++di) o[mi][di][rr] *= al;
        }
      }
      float rs[4] = {0.f, 0.f, 0.f, 0.f};
#pragma unroll
      for (int ni = 0; ni < 4; ++ni)
#pragma unroll
        for (int rr = 0; rr < 4; ++rr) {
          const float pv = exp2f(s[mi][ni][rr] - mrow[mi][rr]);
          rs[rr] += pv;
          const int row = g * 4 + rr;
          smP[w * 2048 + (mi * 16 + row) * 64 + ((ni * 2 + (c >> 3)) ^ (row & 7)) * 8 + (c & 7)] = f2bf(pv);
        }
#pragma unroll
      for (int rr = 0; rr < 4; ++rr) lrow[mi][rr] += rs[rr];
    }

    // ---- O += P V
#pragma unroll
    for (int ks = 0; ks < 2; ++ks) {
      short8 pa[2];
#pragma unroll
      for (int mi = 0; mi < 2; ++mi)
        pa[mi] = *(const short8*)&smP[w * 2048 + (mi * 16 + c) * 64 + (((ks * 4 + g) ^ (c & 7))) * 8];
#pragma unroll
      for (int di = 0; di < 8; ++di) {
        const short8 vf = *(const short8*)&smV[buf * 8192 + (di * 16 + c) * 64 + (((ks * 4 + g) ^ (c & 7))) * 8];
#pragma unroll
        for (int mi = 0; mi < 2; ++mi)
          o[mi][di] = __builtin_amdgcn_mfma_f32_16x16x32_bf16(pa[mi], vf, o[mi][di], 0, 0, 0);
      }
    }

    // ---- write-late: V^T of tile t+1 into buf^1
    if (t + 1 < NT) {
#pragma unroll
      for (int i = 0; i < 8; ++i) {
        const int d = vdg * 8 + i;
        const int slot = (kvp >> 3) ^ (d & 7);
        *(u32*)&smV[nb * 8192 + d * 64 + slot * 8 + (kvp & 7)] = (u32)va[i] | ((u32)vb2[i] << 16);
      }
    }
    __syncthreads();
    buf = nb;
  }

  // ---- finalize: reduce l across the 16-lane col group, divide, store
#pragma unroll
  for (int mi = 0; mi < 2; ++mi) {
#pragma unroll
    for (int off = 8; off >= 1; off >>= 1)
#pragma unroll
      for (int rr = 0; rr < 4; ++rr)
        lrow[mi][rr] += __shfl_xor(lrow[mi][rr], off);
    float inv[4];
#pragma unroll
    for (int rr = 0; rr < 4; ++rr) inv[rr] = 1.0f / lrow[mi][rr];
#pragma unroll
    for (int di = 0; di < 8; ++di)
#pragma unroll
      for (int rr = 0; rr < 4; ++rr)
        O[(rowb + q0 + w * 32 + mi * 16 + g * 4 + rr) * DM + hoff + di * 16 + c] =
            f2bf(o[mi][di][rr] * inv[rr]);
  }
}

extern "C" void kernel_launch(void* const* d_in, const int* in_sizes, int n_in,
                              void* d_out, int out_size, void* d_ws, size_t ws_size,
                              hipStream_t stream) {
  const float* x    = (const float*)d_in[0];
  const float* wq_w = (const float*)d_in[1];
  const float* wq_b = (const float*)d_in[2];
  const float* wk_w = (const float*)d_in[3];
  const float* wk_b = (const float*)d_in[4];
  const float* wv_w = (const float*)d_in[5];
  const float* wv_b = (const float*)d_in[6];
  const float* wo_w = (const float*)d_in[7];
  const float* wo_b = (const float*)d_in[8];
  float* out = (float*)d_out;

  u16* p = (u16*)d_ws;
  u16* xb  = p; p += (size_t)NB * SQ * DM;
  u16* wqb = p; p += (size_t)DM * DM;
  u16* wkb = p; p += (size_t)DM * DM;
  u16* wvb = p; p += (size_t)DM * DM;
  u16* wob = p; p += (size_t)DM * DM;
  u16* Qb  = p; p += (size_t)NB * SQ * DM;
  u16* Kb  = p; p += (size_t)NB * SQ * DM;
  u16* Vb  = p; p += (size_t)NB * SQ * DM;
  u16* ctx = xb;  // reuse: x no longer needed after V projection

  const int nx = NB * SQ * DM;
  const int nw = DM * DM;
  cvt_bf16<<<dim3(nx / 1024), dim3(256), 0, stream>>>(x, xb, nx);
  cvt_bf16<<<dim3(nw / 1024), dim3(256), 0, stream>>>(wq_w, wqb, nw);
  cvt_bf16<<<dim3(nw / 1024), dim3(256), 0, stream>>>(wk_w, wkb, nw);
  cvt_bf16<<<dim3(nw / 1024), dim3(256), 0, stream>>>(wv_w, wvb, nw);
  cvt_bf16<<<dim3(nw / 1024), dim3(256), 0, stream>>>(wo_w, wob, nw);

  const float sc2 = 0.08838834764831845f * 1.4426950408889634f;  // 1/sqrt(128)*log2(e)
  dim3 gg(DM / 128, (NB * SQ) / 128);
  gemm_bt<false><<<gg, dim3(256), 0, stream>>>(xb, wqb, wq_b, Qb, NB * SQ, DM, DM, sc2);
  gemm_bt<false><<<gg, dim3(256), 0, stream>>>(xb, wkb, wk_b, Kb, NB * SQ, DM, DM, 1.0f);
  gemm_bt<false><<<gg, dim3(256), 0, stream>>>(xb, wvb, wv_b, Vb, NB * SQ, DM, DM, 1.0f);

  attn<<<dim3(SQ / 256, NH, NB), dim3(512), 0, stream>>>(Qb, Kb, Vb, ctx);

  gemm_bt<true><<<gg, dim3(256), 0, stream>>>(ctx, wob, wo_b, out, NB * SQ, DM, DM, 1.0f);
}

// Round 3
// 703.285 us; speedup vs baseline: 1.3955x; 1.1215x over previous
//
#include <hip/hip_runtime.h>
#include <hip/hip_bf16.h>
#include <math.h>

typedef __attribute__((ext_vector_type(8))) short short8;
typedef __attribute__((ext_vector_type(4))) float f32x4;
typedef __attribute__((ext_vector_type(16))) float f32x16;
typedef __attribute__((ext_vector_type(4))) unsigned short u16x4;
typedef __attribute__((ext_vector_type(8))) unsigned short u16x8;
typedef __attribute__((ext_vector_type(4))) unsigned int u32x4;
typedef __attribute__((ext_vector_type(2))) int i32x2;
typedef unsigned short u16;
typedef unsigned int u32;

#define DM 2048
#define SQ 2048
#define NB 4
#define NH 16
#define DKH 128
#define KT 64
#define NT (SQ / KT)

__device__ __forceinline__ u16 f2bf(float f) {
  unsigned u = __float_as_uint(f);
  u += 0x7fffu + ((u >> 16) & 1u);
  return (u16)(u >> 16);
}

__device__ __forceinline__ u32 cvtpk(float lo, float hi) {
  u32 r;
  asm("v_cvt_pk_bf16_f32 %0, %1, %2" : "=v"(r) : "v"(lo), "v"(hi));
  return r;
}

__device__ __forceinline__ void gload16(const u16* g, u16* lds) {
  __builtin_amdgcn_global_load_lds(
      (const __attribute__((address_space(1))) unsigned int*)g,
      (__attribute__((address_space(3))) unsigned int*)lds, 16, 0, 0);
}

__global__ void cvt_bf16(const float* __restrict__ in, u16* __restrict__ out, int n) {
  int i = (blockIdx.x * blockDim.x + threadIdx.x) * 4;
  if (i >= n) return;
  float4 v = *(const float4*)(in + i);
  u16x4 o;
  o.x = f2bf(v.x); o.y = f2bf(v.y); o.z = f2bf(v.z); o.w = f2bf(v.w);
  *(u16x4*)(out + i) = o;
}

// C = (A @ B^T + bias) * oscale.  A: [M][K] bf16, B: [N][K] bf16, bias: [N] f32.
template <bool OUTF32>
__global__ __launch_bounds__(256) void gemm_bt(
    const u16* __restrict__ A, const u16* __restrict__ B,
    const float* __restrict__ bias, void* __restrict__ Cout,
    int M, int N, int K, float oscale) {
  __shared__ u16 smA[128 * 32];
  __shared__ u16 smB[128 * 32];
  const int tid = threadIdx.x;
  const int w = tid >> 6, l = tid & 63;
  const int g = l >> 4, c = l & 15;

  // XCD-aware swizzle (nwg % 8 == 0 for all our launches)
  int flat = blockIdx.x + (int)gridDim.x * (int)blockIdx.y;
  const int nwg = (int)(gridDim.x * gridDim.y);
  flat = (flat & 7) * (nwg >> 3) + (flat >> 3);
  const int m0 = (flat / (int)gridDim.x) * 128, n0 = (flat % (int)gridDim.x) * 128;
  const int wr = w >> 1, wc = w & 1;

  f32x4 acc[4][4] = {};

  const int srow = w * 32 + (l >> 2);
  const int scol = (l & 3) * 8;
  const u16* Abase = A + (size_t)(m0 + srow) * K + scol;
  const u16* Bbase = B + (size_t)(n0 + srow) * K + scol;
  u16* ldsA = &smA[(w * 32) * 32];
  u16* ldsB = &smB[(w * 32) * 32];

  for (int kt = 0; kt < K; kt += 32) {
    __syncthreads();
    gload16(Abase + kt, ldsA);
    gload16(Abase + (size_t)16 * K + kt, ldsA + 16 * 32);
    gload16(Bbase + kt, ldsB);
    gload16(Bbase + (size_t)16 * K + kt, ldsB + 16 * 32);
    __syncthreads();
    short8 a[4], b[4];
#pragma unroll
    for (int mi = 0; mi < 4; ++mi)
      a[mi] = *(const short8*)&smA[(wr * 64 + mi * 16 + c) * 32 + g * 8];
#pragma unroll
    for (int ni = 0; ni < 4; ++ni)
      b[ni] = *(const short8*)&smB[(wc * 64 + ni * 16 + c) * 32 + g * 8];
#pragma unroll
    for (int mi = 0; mi < 4; ++mi)
#pragma unroll
      for (int ni = 0; ni < 4; ++ni)
        acc[mi][ni] = __builtin_amdgcn_mfma_f32_16x16x32_bf16(a[mi], b[ni], acc[mi][ni], 0, 0, 0);
  }

#pragma unroll
  for (int mi = 0; mi < 4; ++mi)
#pragma unroll
    for (int ni = 0; ni < 4; ++ni) {
      const int col = n0 + wc * 64 + ni * 16 + c;
      const float bv = bias[col];
#pragma unroll
      for (int rr = 0; rr < 4; ++rr) {
        const int row = m0 + wr * 64 + mi * 16 + g * 4 + rr;
        const float v = (acc[mi][ni][rr] + bv) * oscale;
        if (OUTF32)
          ((float*)Cout)[(size_t)row * N + col] = v;
        else
          ((u16*)Cout)[(size_t)row * N + col] = f2bf(v);
      }
    }
}

// Flash attention: 8 waves x 32 q = 256 q/block, KV tiles of 64, 32x32x16 MFMA,
// swapped QK^T (S^T = mfma(K,Q)) -> in-register softmax (permlane32_swap),
// P->A-frag via cvt_pk_bf16 + permlane32_swap (no P LDS), double-buffered K/V.
__global__ __launch_bounds__(512, 2) void attn(
    const u16* __restrict__ Q, const u16* __restrict__ K,
    const u16* __restrict__ V, u16* __restrict__ O) {
  // K: [buf][kv 64][256B rows: 16 slots of 16B, slot ^= row&15]
  __shared__ u16 smK[2 * 8192];
  // V^T: [buf][d 128][144B rows: 64 kv + 8 pad]
  __shared__ u16 smV[2 * 9216];
  __shared__ float alScr[8 * 32];

  const int tid = threadIdx.x;
  const int w = tid >> 6, l = tid & 63;
  const int c5 = l & 31, hi = l >> 5;

  // XCD swizzle: all 8 q-tiles of 8 (h,b) pairs land on one XCD
  int flat = blockIdx.x + ((int)blockIdx.y << 3) + ((int)blockIdx.z << 7);
  flat = (flat & 7) * 64 + (flat >> 3);
  const int qt = flat & 7, h = (flat >> 3) & 15, b = flat >> 7;

  const int q0 = qt * 256 + w * 32;
  const size_t rowb = (size_t)b * SQ;
  const int hoff = h * DKH;

  // Q B-frags: lane (c5,hi) holds Q[q0+c5][d = ds*16 + hi*8 + j] (pre-scaled)
  short8 qf[8];
#pragma unroll
  for (int ds = 0; ds < 8; ++ds)
    qf[ds] = *(const short8*)&Q[(rowb + q0 + c5) * DM + hoff + ds * 16 + hi * 8];

  f32x16 o[4] = {};
  float mrow = -1e30f, lsum = 0.f;

  const int vdg = tid >> 5;        // 0..15: d-block of 8
  const int kvp = (tid & 31) * 2;  // kv pair base
  u16x8 va, vb;

  // ---- prologue: stage tile 0 into buf 0 ----
  {
    const u16* vp = &V[(rowb + kvp) * DM + hoff + vdg * 8];
    va = *(const u16x8*)vp;
    vb = *(const u16x8*)(vp + DM);
#pragma unroll
    for (int uu = 0; uu < 2; ++uu) {
      const int u = w * 2 + uu;
      const int row = u * 4 + (l >> 4);
      const int col16 = (l & 15) ^ (row & 15);
      gload16(&K[(rowb + row) * DM + hoff + col16 * 8], &smK[u * 512]);
    }
#pragma unroll
    for (int i = 0; i < 8; ++i) {
      const int d = vdg * 8 + i;
      *(u32*)&smV[d * 72 + kvp] = (u32)va[i] | ((u32)vb[i] << 16);
    }
  }
  __syncthreads();

  int buf = 0;
  for (int t = 0; t < NT; ++t) {
    const int nb = buf ^ 1;
    // ---- issue-early prefetch of tile t+1 ----
    if (t + 1 < NT) {
      const size_t kvr = rowb + (size_t)(t + 1) * KT;
      const u16* vp = &V[(kvr + kvp) * DM + hoff + vdg * 8];
      va = *(const u16x8*)vp;
      vb = *(const u16x8*)(vp + DM);
#pragma unroll
      for (int uu = 0; uu < 2; ++uu) {
        const int u = w * 2 + uu;
        const int row = u * 4 + (l >> 4);
        const int col16 = (l & 15) ^ (row & 15);
        gload16(&K[(kvr + row) * DM + hoff + col16 * 8], &smK[nb * 8192 + u * 512]);
      }
    }

    // ---- S^T = mfma(K, Q): lane (c5,hi) reg r -> S[kv=32ni+(r&3)+8(r>>2)+4hi][q=c5]
    f32x16 s[2] = {};
    __builtin_amdgcn_s_setprio(1);
#pragma unroll
    for (int ni = 0; ni < 2; ++ni) {
      const int row = ni * 32 + c5;
#pragma unroll
      for (int ds = 0; ds < 8; ++ds) {
        const short8 kf = *(const short8*)&smK[buf * 8192 + row * 128 + (((ds << 1) | hi) ^ (row & 15)) * 8];
        s[ni] = __builtin_amdgcn_mfma_f32_32x32x16_bf16(kf, qf[ds], s[ni], 0, 0, 0);
      }
    }
    __builtin_amdgcn_s_setprio(0);

    // ---- in-register online softmax (log2 domain; scale folded into Q) ----
    float mx = s[0][0];
#pragma unroll
    for (int ni = 0; ni < 2; ++ni)
#pragma unroll
      for (int i = 0; i < 16; ++i)
        mx = fmaxf(mx, s[ni][i]);
    i32x2 sw = __builtin_amdgcn_permlane32_swap(__float_as_int(mx), __float_as_int(mx), false, false);
    const float gmax = fmaxf(__int_as_float(sw.x), __int_as_float(sw.y));

    if (__any(gmax > mrow + 10.0f)) {
      const float mn = fmaxf(mrow, gmax);
      const float al = exp2f(mrow - mn);
      mrow = mn;
      lsum *= al;
      alScr[w * 32 + c5] = al;  // wave-private scratch; lgkmcnt orders write->read
#pragma unroll
      for (int r = 0; r < 16; ++r) {
        const float av = alScr[w * 32 + (r & 3) + 8 * (r >> 2) + 4 * hi];
#pragma unroll
        for (int dg = 0; dg < 4; ++dg) o[dg][r] *= av;
      }
    }

    float ps0 = 0.f, ps1 = 0.f;
#pragma unroll
    for (int i = 0; i < 16; ++i) {
      const float p0 = exp2f(s[0][i] - mrow);
      const float p1 = exp2f(s[1][i] - mrow);
      s[0][i] = p0; s[1][i] = p1;
      ps0 += p0; ps1 += p1;
    }
    lsum += ps0 + ps1;

    // ---- P -> A-frags (cvt_pk + permlane32_swap), then O += P V ----
    __builtin_amdgcn_s_setprio(1);
#pragma unroll
    for (int ks = 0; ks < 4; ++ks) {
      const int b0 = (ks & 1) * 8;
      const int ni = ks >> 1;
      const u32 A0 = cvtpk(s[ni][b0 + 0], s[ni][b0 + 1]);
      const u32 A1 = cvtpk(s[ni][b0 + 4], s[ni][b0 + 5]);
      const u32 B0 = cvtpk(s[ni][b0 + 2], s[ni][b0 + 3]);
      const u32 B1 = cvtpk(s[ni][b0 + 6], s[ni][b0 + 7]);
      const i32x2 r0 = __builtin_amdgcn_permlane32_swap((int)A0, (int)A1, false, false);
      const i32x2 r1 = __builtin_amdgcn_permlane32_swap((int)B0, (int)B1, false, false);
      u32x4 paw;
      paw.x = (u32)r0.x; paw.y = (u32)r1.x; paw.z = (u32)r0.y; paw.w = (u32)r1.y;
      const short8 pa = *(const short8*)&paw;
#pragma unroll
      for (int dg = 0; dg < 4; ++dg) {
        const int rowd = dg * 32 + c5;
        const short8 vf = *(const short8*)&smV[buf * 9216 + rowd * 72 + ks * 16 + hi * 8];
        o[dg] = __builtin_amdgcn_mfma_f32_32x32x16_bf16(pa, vf, o[dg], 0, 0, 0);
      }
    }
    __builtin_amdgcn_s_setprio(0);

    // ---- write-late: V^T of tile t+1 ----
    if (t + 1 < NT) {
#pragma unroll
      for (int i = 0; i < 8; ++i) {
        const int d = vdg * 8 + i;
        *(u32*)&smV[nb * 9216 + d * 72 + kvp] = (u32)va[i] | ((u32)vb[i] << 16);
      }
    }
    __syncthreads();
    buf = nb;
  }

  // ---- finalize: total l across halves, divide, store bf16 ----
  {
    const i32x2 sl = __builtin_amdgcn_permlane32_swap(__float_as_int(lsum), __float_as_int(lsum), false, false);
    const float tot = __int_as_float(sl.x) + __int_as_float(sl.y);
    alScr[w * 32 + c5] = 1.0f / tot;
  }
#pragma unroll
  for (int r = 0; r < 16; ++r) {
    const int qloc = (r & 3) + 8 * (r >> 2) + 4 * hi;
    const float inv = alScr[w * 32 + qloc];
    const size_t orow = (rowb + q0 + qloc) * DM + hoff;
#pragma unroll
    for (int dg = 0; dg < 4; ++dg)
      O[orow + dg * 32 + c5] = f2bf(o[dg][r] * inv);
  }
}

extern "C" void kernel_launch(void* const* d_in, const int* in_sizes, int n_in,
                              void* d_out, int out_size, void* d_ws, size_t ws_size,
                              hipStream_t stream) {
  const float* x    = (const float*)d_in[0];
  const float* wq_w = (const float*)d_in[1];
  const float* wq_b = (const float*)d_in[2];
  const float* wk_w = (const float*)d_in[3];
  const float* wk_b = (const float*)d_in[4];
  const float* wv_w = (const float*)d_in[5];
  const float* wv_b = (const float*)d_in[6];
  const float* wo_w = (const float*)d_in[7];
  const float* wo_b = (const float*)d_in[8];
  float* out = (float*)d_out;

  u16* p = (u16*)d_ws;
  u16* xb  = p; p += (size_t)NB * SQ * DM;
  u16* wqb = p; p += (size_t)DM * DM;
  u16* wkb = p; p += (size_t)DM * DM;
  u16* wvb = p; p += (size_t)DM * DM;
  u16* wob = p; p += (size_t)DM * DM;
  u16* Qb  = p; p += (size_t)NB * SQ * DM;
  u16* Kb  = p; p += (size_t)NB * SQ * DM;
  u16* Vb  = p; p += (size_t)NB * SQ * DM;
  u16* ctx = xb;  // reuse: x no longer needed after V projection

  const int nx = NB * SQ * DM;
  const int nw = DM * DM;
  cvt_bf16<<<dim3(nx / 1024), dim3(256), 0, stream>>>(x, xb, nx);
  cvt_bf16<<<dim3(nw / 1024), dim3(256), 0, stream>>>(wq_w, wqb, nw);
  cvt_bf16<<<dim3(nw / 1024), dim3(256), 0, stream>>>(wk_w, wkb, nw);
  cvt_bf16<<<dim3(nw / 1024), dim3(256), 0, stream>>>(wv_w, wvb, nw);
  cvt_bf16<<<dim3(nw / 1024), dim3(256), 0, stream>>>(wo_w, wob, nw);

  const float sc2 = 0.08838834764831845f * 1.4426950408889634f;  // 1/sqrt(128)*log2(e)
  dim3 gg(DM / 128, (NB * SQ) / 128);
  gemm_bt<false><<<gg, dim3(256), 0, stream>>>(xb, wqb, wq_b, Qb, NB * SQ, DM, DM, sc2);
  gemm_bt<false><<<gg, dim3(256), 0, stream>>>(xb, wkb, wk_b, Kb, NB * SQ, DM, DM, 1.0f);
  gemm_bt<false><<<gg, dim3(256), 0, stream>>>(xb, wvb, wv_b, Vb, NB * SQ, DM, DM, 1.0f);

  attn<<<dim3(SQ / 256, NH, NB), dim3(512), 0, stream>>>(Qb, Kb, Vb, ctx);

  gemm_bt<true><<<gg, dim3(256), 0, stream>>>(ctx, wob, wo_b, out, NB * SQ, DM, DM, 1.0f);
}

// Round 4
// 617.547 us; speedup vs baseline: 1.5892x; 1.1388x over previous
//
#include <hip/hip_runtime.h>
#include <hip/hip_bf16.h>
#include <math.h>

typedef __attribute__((ext_vector_type(8))) short short8;
typedef __attribute__((ext_vector_type(4))) float f32x4;
typedef __attribute__((ext_vector_type(16))) float f32x16;
typedef __attribute__((ext_vector_type(4))) unsigned short u16x4;
typedef __attribute__((ext_vector_type(8))) unsigned short u16x8;
typedef __attribute__((ext_vector_type(4))) unsigned int u32x4;
typedef __attribute__((ext_vector_type(2))) int i32x2;
typedef unsigned short u16;
typedef unsigned int u32;

#define DM 2048
#define SQ 2048
#define NB 4
#define NH 16
#define DKH 128
#define KT 64
#define NT (SQ / KT)

__device__ __forceinline__ u16 f2bf(float f) {
  unsigned u = __float_as_uint(f);
  u += 0x7fffu + ((u >> 16) & 1u);
  return (u16)(u >> 16);
}

__device__ __forceinline__ u32 cvtpk(float lo, float hi) {
  u32 r;
  asm("v_cvt_pk_bf16_f32 %0, %1, %2" : "=v"(r) : "v"(lo), "v"(hi));
  return r;
}

__device__ __forceinline__ void gload16(const u16* g, u16* lds) {
  __builtin_amdgcn_global_load_lds(
      (const __attribute__((address_space(1))) unsigned int*)g,
      (__attribute__((address_space(3))) unsigned int*)lds, 16, 0, 0);
}

__global__ void cvt_bf16(const float* __restrict__ in, u16* __restrict__ out, int n) {
  int i = (blockIdx.x * blockDim.x + threadIdx.x) * 4;
  if (i >= n) return;
  float4 v = *(const float4*)(in + i);
  u16x4 o;
  o.x = f2bf(v.x); o.y = f2bf(v.y); o.z = f2bf(v.z); o.w = f2bf(v.w);
  *(u16x4*)(out + i) = o;
}

// 4 weight matrices -> contiguous bf16 dst (blockIdx.y selects source)
__global__ void cvt_w4(const float* __restrict__ w0, const float* __restrict__ w1,
                       const float* __restrict__ w2, const float* __restrict__ w3,
                       u16* __restrict__ dst) {
  const int sel = blockIdx.y;
  const float* src;
  switch (sel) {
    case 0: src = w0; break;
    case 1: src = w1; break;
    case 2: src = w2; break;
    default: src = w3; break;
  }
  const int i = (blockIdx.x * blockDim.x + threadIdx.x) * 4;
  float4 v = *(const float4*)(src + i);
  u16x4 o;
  o.x = f2bf(v.x); o.y = f2bf(v.y); o.z = f2bf(v.z); o.w = f2bf(v.w);
  *(u16x4*)(dst + (size_t)sel * DM * DM + i) = o;
}

// ---------------- 256x256-tile pipelined GEMM ----------------
// C = (A @ B^T + bias) * oscale.  A: [M][K] bf16, B: [N][K] bf16, bias [N] f32.
// 8 waves (2Mx4N), per-wave 128x64 via mfma_f32_32x32x16_bf16.
// BK=32, 4-slot LDS ring, prefetch distance 3, counted vmcnt (never 0 in loop).
// LDS rows 64B (4 x 16B slots), slot ^= row&3; staged via pre-swizzled global src.

#define VM8 asm volatile("s_waitcnt vmcnt(8)" ::: "memory")
#define VM4 asm volatile("s_waitcnt vmcnt(4)" ::: "memory")
#define VM0 asm volatile("s_waitcnt vmcnt(0)" ::: "memory")

#define STAGE(T)                                                        \
  do {                                                                  \
    const size_t ko_ = (size_t)(T) * 32;                                \
    const int bb_ = ((T) & 3) * 8192;                                   \
    gload16(Abase + ko_, &smA[bb_ + w * 1024]);                         \
    gload16(Abase + (size_t)16 * K + ko_, &smA[bb_ + w * 1024 + 512]);  \
    gload16(Bbase + ko_, &smB[bb_ + w * 1024]);                         \
    gload16(Bbase + (size_t)16 * K + ko_, &smB[bb_ + w * 1024 + 512]);  \
  } while (0)

#define GITER(T, VMOP, DOSTG)                                                          \
  do {                                                                                 \
    const int bi_ = (T) & 3;                                                           \
    const u16* pA_ = &smA[bi_ * 8192];                                                 \
    const u16* pB_ = &smB[bi_ * 8192];                                                 \
    short8 af_[2][4], bf_[2][2];                                                       \
    _Pragma("unroll") for (int kk = 0; kk < 2; ++kk) {                                 \
      const int sl_ = (((kk << 1) | hi) ^ (c5 & 3)) << 3;                              \
      _Pragma("unroll") for (int mf = 0; mf < 4; ++mf)                                 \
        af_[kk][mf] = *(const short8*)&pA_[(wr * 128 + mf * 32 + c5) * 32 + sl_];      \
      _Pragma("unroll") for (int nf = 0; nf < 2; ++nf)                                 \
        bf_[kk][nf] = *(const short8*)&pB_[(wc * 64 + nf * 32 + c5) * 32 + sl_];       \
    }                                                                                  \
    if (DOSTG) STAGE((T) + 3);                                                         \
    __builtin_amdgcn_s_barrier();                                                      \
    asm volatile("s_waitcnt lgkmcnt(0)" ::: "memory");                                 \
    __builtin_amdgcn_sched_barrier(0);                                                 \
    __builtin_amdgcn_s_setprio(1);                                                     \
    _Pragma("unroll") for (int kk = 0; kk < 2; ++kk)                                   \
      _Pragma("unroll") for (int mf = 0; mf < 4; ++mf)                                 \
        _Pragma("unroll") for (int nf = 0; nf < 2; ++nf)                               \
          acc[mf][nf] =                                                                \
              __builtin_amdgcn_mfma_f32_32x32x16_bf16(af_[kk][mf], bf_[kk][nf],        \
                                                      acc[mf][nf], 0, 0, 0);           \
    __builtin_amdgcn_s_setprio(0);                                                     \
    VMOP;                                                                              \
    __builtin_amdgcn_s_barrier();                                                      \
  } while (0)

template <bool OUTF32>
__global__ __launch_bounds__(512, 2) void gemm_bt2(
    const u16* __restrict__ A, const u16* __restrict__ B,
    const float* __restrict__ bias, void* __restrict__ Cout,
    int M, int N, int K, float oscale) {
  __shared__ u16 smA[4 * 8192];  // [slot4][256 rows][32 elems], 64B rows, swizzled
  __shared__ u16 smB[4 * 8192];
  const int tid = threadIdx.x;
  const int w = tid >> 6, l = tid & 63;
  const int c5 = l & 31, hi = l >> 5;
  const int wr = w >> 2, wc = w & 3;
  const int m0 = blockIdx.y * 256, n0 = blockIdx.x * 256;
  const int NSTEP = K / 32;

  f32x16 acc[4][2] = {};

  // staging geometry: seg = w*2+u covers rows seg*16..+15; lane l -> row seg*16+(l>>2),
  // phys slot l&3 holds global k-chunk (l&3)^((l>>2)&3)  (pre-swizzled source)
  const int srow = w * 32 + (l >> 2);
  const int scol = ((l & 3) ^ ((l >> 2) & 3)) * 8;
  const u16* Abase = A + (size_t)(m0 + srow) * K + scol;
  const u16* Bbase = B + (size_t)(n0 + srow) * K + scol;

  STAGE(0); STAGE(1); STAGE(2);
  VM8;  // stage 0 resident (12 outstanding -> wait to 8)
  __builtin_amdgcn_s_barrier();

  for (int t = 0; t < NSTEP - 3; ++t) GITER(t, VM8, true);
  GITER(NSTEP - 3, VM4, false);
  GITER(NSTEP - 2, VM0, false);
  GITER(NSTEP - 1, ((void)0), false);

  // epilogue: C[row][col], row = m0+wr*128+mf*32+(r&3)+8*(r>>2)+4*hi, col = n0+wc*64+nf*32+c5
#pragma unroll
  for (int nf = 0; nf < 2; ++nf) {
    const int col = n0 + wc * 64 + nf * 32 + c5;
    const float bv = bias[col];
#pragma unroll
    for (int mf = 0; mf < 4; ++mf) {
#pragma unroll
      for (int r = 0; r < 16; ++r) {
        const int row = m0 + wr * 128 + mf * 32 + (r & 3) + 8 * (r >> 2) + 4 * hi;
        const float v = (acc[mf][nf][r] + bv) * oscale;
        if (OUTF32)
          ((float*)Cout)[(size_t)row * N + col] = v;
        else
          ((u16*)Cout)[(size_t)row * N + col] = f2bf(v);
      }
    }
  }
}

// Flash attention: 8 waves x 32 q = 256 q/block, KV tiles of 64, 32x32x16 MFMA,
// swapped QK^T (S^T = mfma(K,Q)) -> in-register softmax (permlane32_swap),
// P->A-frag via cvt_pk_bf16 + permlane32_swap (no P LDS), double-buffered K/V.
__global__ __launch_bounds__(512, 2) void attn(
    const u16* __restrict__ Q, const u16* __restrict__ K,
    const u16* __restrict__ V, u16* __restrict__ O) {
  __shared__ u16 smK[2 * 8192];
  __shared__ u16 smV[2 * 9216];
  __shared__ float alScr[8 * 32];

  const int tid = threadIdx.x;
  const int w = tid >> 6, l = tid & 63;
  const int c5 = l & 31, hi = l >> 5;

  int flat = blockIdx.x + ((int)blockIdx.y << 3) + ((int)blockIdx.z << 7);
  flat = (flat & 7) * 64 + (flat >> 3);
  const int qt = flat & 7, h = (flat >> 3) & 15, b = flat >> 7;

  const int q0 = qt * 256 + w * 32;
  const size_t rowb = (size_t)b * SQ;
  const int hoff = h * DKH;

  short8 qf[8];
#pragma unroll
  for (int ds = 0; ds < 8; ++ds)
    qf[ds] = *(const short8*)&Q[(rowb + q0 + c5) * DM + hoff + ds * 16 + hi * 8];

  f32x16 o[4] = {};
  float mrow = -1e30f, lsum = 0.f;

  const int vdg = tid >> 5;
  const int kvp = (tid & 31) * 2;
  u16x8 va, vb;

  {
    const u16* vp = &V[(rowb + kvp) * DM + hoff + vdg * 8];
    va = *(const u16x8*)vp;
    vb = *(const u16x8*)(vp + DM);
#pragma unroll
    for (int uu = 0; uu < 2; ++uu) {
      const int u = w * 2 + uu;
      const int row = u * 4 + (l >> 4);
      const int col16 = (l & 15) ^ (row & 15);
      gload16(&K[(rowb + row) * DM + hoff + col16 * 8], &smK[u * 512]);
    }
#pragma unroll
    for (int i = 0; i < 8; ++i) {
      const int d = vdg * 8 + i;
      *(u32*)&smV[d * 72 + kvp] = (u32)va[i] | ((u32)vb[i] << 16);
    }
  }
  __syncthreads();

  int buf = 0;
  for (int t = 0; t < NT; ++t) {
    const int nb = buf ^ 1;
    if (t + 1 < NT) {
      const size_t kvr = rowb + (size_t)(t + 1) * KT;
      const u16* vp = &V[(kvr + kvp) * DM + hoff + vdg * 8];
      va = *(const u16x8*)vp;
      vb = *(const u16x8*)(vp + DM);
#pragma unroll
      for (int uu = 0; uu < 2; ++uu) {
        const int u = w * 2 + uu;
        const int row = u * 4 + (l >> 4);
        const int col16 = (l & 15) ^ (row & 15);
        gload16(&K[(kvr + row) * DM + hoff + col16 * 8], &smK[nb * 8192 + u * 512]);
      }
    }

    f32x16 s[2] = {};
    __builtin_amdgcn_s_setprio(1);
#pragma unroll
    for (int ni = 0; ni < 2; ++ni) {
      const int row = ni * 32 + c5;
#pragma unroll
      for (int ds = 0; ds < 8; ++ds) {
        const short8 kf = *(const short8*)&smK[buf * 8192 + row * 128 + (((ds << 1) | hi) ^ (row & 15)) * 8];
        s[ni] = __builtin_amdgcn_mfma_f32_32x32x16_bf16(kf, qf[ds], s[ni], 0, 0, 0);
      }
    }
    __builtin_amdgcn_s_setprio(0);

    float mx = s[0][0];
#pragma unroll
    for (int ni = 0; ni < 2; ++ni)
#pragma unroll
      for (int i = 0; i < 16; ++i)
        mx = fmaxf(mx, s[ni][i]);
    i32x2 sw = __builtin_amdgcn_permlane32_swap(__float_as_int(mx), __float_as_int(mx), false, false);
    const float gmax = fmaxf(__int_as_float(sw.x), __int_as_float(sw.y));

    if (__any(gmax > mrow + 10.0f)) {
      const float mn = fmaxf(mrow, gmax);
      const float al = exp2f(mrow - mn);
      mrow = mn;
      lsum *= al;
      alScr[w * 32 + c5] = al;
#pragma unroll
      for (int r = 0; r < 16; ++r) {
        const float av = alScr[w * 32 + (r & 3) + 8 * (r >> 2) + 4 * hi];
#pragma unroll
        for (int dg = 0; dg < 4; ++dg) o[dg][r] *= av;
      }
    }

    float ps0 = 0.f, ps1 = 0.f;
#pragma unroll
    for (int i = 0; i < 16; ++i) {
      const float p0 = exp2f(s[0][i] - mrow);
      const float p1 = exp2f(s[1][i] - mrow);
      s[0][i] = p0; s[1][i] = p1;
      ps0 += p0; ps1 += p1;
    }
    lsum += ps0 + ps1;

    __builtin_amdgcn_s_setprio(1);
#pragma unroll
    for (int ks = 0; ks < 4; ++ks) {
      const int b0 = (ks & 1) * 8;
      const int ni = ks >> 1;
      const u32 A0 = cvtpk(s[ni][b0 + 0], s[ni][b0 + 1]);
      const u32 A1 = cvtpk(s[ni][b0 + 4], s[ni][b0 + 5]);
      const u32 B0 = cvtpk(s[ni][b0 + 2], s[ni][b0 + 3]);
      const u32 B1 = cvtpk(s[ni][b0 + 6], s[ni][b0 + 7]);
      const i32x2 r0 = __builtin_amdgcn_permlane32_swap((int)A0, (int)A1, false, false);
      const i32x2 r1 = __builtin_amdgcn_permlane32_swap((int)B0, (int)B1, false, false);
      u32x4 paw;
      paw.x = (u32)r0.x; paw.y = (u32)r1.x; paw.z = (u32)r0.y; paw.w = (u32)r1.y;
      const short8 pa = *(const short8*)&paw;
#pragma unroll
      for (int dg = 0; dg < 4; ++dg) {
        const int rowd = dg * 32 + c5;
        const short8 vf = *(const short8*)&smV[buf * 9216 + rowd * 72 + ks * 16 + hi * 8];
        o[dg] = __builtin_amdgcn_mfma_f32_32x32x16_bf16(pa, vf, o[dg], 0, 0, 0);
      }
    }
    __builtin_amdgcn_s_setprio(0);

    if (t + 1 < NT) {
#pragma unroll
      for (int i = 0; i < 8; ++i) {
        const int d = vdg * 8 + i;
        *(u32*)&smV[nb * 9216 + d * 72 + kvp] = (u32)va[i] | ((u32)vb[i] << 16);
      }
    }
    __syncthreads();
    buf = nb;
  }

  {
    const i32x2 sl = __builtin_amdgcn_permlane32_swap(__float_as_int(lsum), __float_as_int(lsum), false, false);
    const float tot = __int_as_float(sl.x) + __int_as_float(sl.y);
    alScr[w * 32 + c5] = 1.0f / tot;
  }
#pragma unroll
  for (int r = 0; r < 16; ++r) {
    const int qloc = (r & 3) + 8 * (r >> 2) + 4 * hi;
    const float inv = alScr[w * 32 + qloc];
    const size_t orow = (rowb + q0 + qloc) * DM + hoff;
#pragma unroll
    for (int dg = 0; dg < 4; ++dg)
      O[orow + dg * 32 + c5] = f2bf(o[dg][r] * inv);
  }
}

extern "C" void kernel_launch(void* const* d_in, const int* in_sizes, int n_in,
                              void* d_out, int out_size, void* d_ws, size_t ws_size,
                              hipStream_t stream) {
  const float* x    = (const float*)d_in[0];
  const float* wq_w = (const float*)d_in[1];
  const float* wq_b = (const float*)d_in[2];
  const float* wk_w = (const float*)d_in[3];
  const float* wk_b = (const float*)d_in[4];
  const float* wv_w = (const float*)d_in[5];
  const float* wv_b = (const float*)d_in[6];
  const float* wo_w = (const float*)d_in[7];
  const float* wo_b = (const float*)d_in[8];
  float* out = (float*)d_out;

  u16* p = (u16*)d_ws;
  u16* xb  = p; p += (size_t)NB * SQ * DM;
  u16* wqb = p; p += (size_t)DM * DM;
  u16* wkb = p; p += (size_t)DM * DM;
  u16* wvb = p; p += (size_t)DM * DM;
  u16* wob = p; p += (size_t)DM * DM;
  u16* Qb  = p; p += (size_t)NB * SQ * DM;
  u16* Kb  = p; p += (size_t)NB * SQ * DM;
  u16* Vb  = p; p += (size_t)NB * SQ * DM;
  u16* ctx = xb;  // reuse: x no longer needed after V projection

  const int nx = NB * SQ * DM;
  cvt_bf16<<<dim3(nx / 1024), dim3(256), 0, stream>>>(x, xb, nx);
  cvt_w4<<<dim3(DM * DM / 1024, 4), dim3(256), 0, stream>>>(wq_w, wk_w, wv_w, wo_w, wqb);

  const float sc2 = 0.08838834764831845f * 1.4426950408889634f;  // 1/sqrt(128)*log2(e)
  dim3 gg(DM / 256, (NB * SQ) / 256);
  gemm_bt2<false><<<gg, dim3(512), 0, stream>>>(xb, wqb, wq_b, Qb, NB * SQ, DM, DM, sc2);
  gemm_bt2<false><<<gg, dim3(512), 0, stream>>>(xb, wkb, wk_b, Kb, NB * SQ, DM, DM, 1.0f);
  gemm_bt2<false><<<gg, dim3(512), 0, stream>>>(xb, wvb, wv_b, Vb, NB * SQ, DM, DM, 1.0f);

  attn<<<dim3(SQ / 256, NH, NB), dim3(512), 0, stream>>>(Qb, Kb, Vb, ctx);

  gemm_bt2<true><<<gg, dim3(512), 0, stream>>>(ctx, wob, wo_b, out, NB * SQ, DM, DM, 1.0f);
}

// Round 5
// 563.577 us; speedup vs baseline: 1.7414x; 1.0958x over previous
//
#include <hip/hip_runtime.h>
#include <hip/hip_bf16.h>
#include <math.h>

typedef __attribute__((ext_vector_type(8))) short short8;
typedef __attribute__((ext_vector_type(4))) float f32x4;
typedef __attribute__((ext_vector_type(16))) float f32x16;
typedef __attribute__((ext_vector_type(4))) unsigned short u16x4;
typedef __attribute__((ext_vector_type(8))) unsigned short u16x8;
typedef __attribute__((ext_vector_type(4))) unsigned int u32x4;
typedef __attribute__((ext_vector_type(2))) int i32x2;
typedef unsigned short u16;
typedef unsigned int u32;

#define DM 2048
#define SQ 2048
#define NB 4
#define NH 16
#define DKH 128
#define KT 64
#define NT (SQ / KT)

__device__ __forceinline__ u16 f2bf(float f) {
  unsigned u = __float_as_uint(f);
  u += 0x7fffu + ((u >> 16) & 1u);
  return (u16)(u >> 16);
}

__device__ __forceinline__ u32 cvtpk(float lo, float hi) {
  u32 r;
  asm("v_cvt_pk_bf16_f32 %0, %1, %2" : "=v"(r) : "v"(lo), "v"(hi));
  return r;
}

__device__ __forceinline__ void gload16(const u16* g, u16* lds) {
  __builtin_amdgcn_global_load_lds(
      (const __attribute__((address_space(1))) unsigned int*)g,
      (__attribute__((address_space(3))) unsigned int*)lds, 16, 0, 0);
}

__global__ void cvt_bf16(const float* __restrict__ in, u16* __restrict__ out, int n) {
  int i = (blockIdx.x * blockDim.x + threadIdx.x) * 4;
  if (i >= n) return;
  float4 v = *(const float4*)(in + i);
  u16x4 o;
  o.x = f2bf(v.x); o.y = f2bf(v.y); o.z = f2bf(v.z); o.w = f2bf(v.w);
  *(u16x4*)(out + i) = o;
}

// 4 weight matrices -> contiguous bf16 dst (blockIdx.y selects source)
__global__ void cvt_w4(const float* __restrict__ w0, const float* __restrict__ w1,
                       const float* __restrict__ w2, const float* __restrict__ w3,
                       u16* __restrict__ dst) {
  const int sel = blockIdx.y;
  const float* src;
  switch (sel) {
    case 0: src = w0; break;
    case 1: src = w1; break;
    case 2: src = w2; break;
    default: src = w3; break;
  }
  const int i = (blockIdx.x * blockDim.x + threadIdx.x) * 4;
  float4 v = *(const float4*)(src + i);
  u16x4 o;
  o.x = f2bf(v.x); o.y = f2bf(v.y); o.z = f2bf(v.z); o.w = f2bf(v.w);
  *(u16x4*)(dst + (size_t)sel * DM * DM + i) = o;
}

// ---------------- 256x256 8-phase pipelined GEMM (m201 template port) ----------
// C = (A @ B^T + bias) * oscale.  A: [M][K] bf16, B: [N][K] bf16, bias [N] f32.
// 8 waves (2Mx4N), per-wave C = 128x64 via mfma_f32_32x32x16_bf16.
// BK=64, 2 K-tile double buffer, 4 phases/tile: each phase = {frag ds_reads ||
// stage 1 half-tile} -> barrier -> lgkmcnt(0) -> 8 MFMA (one C-quadrant) -> barrier.
// Stage rotation during tile t: P0:B1(t+1) P1:A1(t+1) P2:B0(t+2) P3:A0(t+2)
// (each half staged only after its LDS region's reads are barrier-confirmed).
// Boundary vmcnt(4) only (counted, never 0 in main loop).
// LDS rows 128B = 8 x 16B slots, slot ^= row&7, staged via pre-swizzled source.

#define STG_A(T, HALF)                                                \
  do {                                                                \
    u16* d_ = &smA[((T) & 1) * 16384 + (((HALF) * 128 + w * 16) << 6)]; \
    const u16* s_ = As + (size_t)((HALF) * 128) * K + (size_t)(T) * 64; \
    gload16(s_, d_);                                                  \
    gload16(s_ + (size_t)8 * K, d_ + 8 * 64);                         \
  } while (0)

#define STG_B(T, HALF)                                                \
  do {                                                                \
    u16* d_ = &smB[((T) & 1) * 16384 + (((HALF) * 128 + w * 16) << 6)]; \
    const u16* s_ = Bs + (size_t)((HALF) * 128) * K + (size_t)(T) * 64; \
    gload16(s_, d_);                                                  \
    gload16(s_ + (size_t)8 * K, d_ + 8 * 64);                         \
  } while (0)

#define LDA(QM)                                                          \
  do {                                                                   \
    const u16* p_ = &smA[bi * 16384 + ((wr * 128 + (QM) * 64 + c5) << 6)]; \
    _Pragma("unroll") for (int s = 0; s < 4; ++s) {                      \
      const int sl_ = (((s << 1) | hi) ^ (c5 & 7)) << 3;                 \
      af[0][s] = *(const short8*)&p_[sl_];                               \
      af[1][s] = *(const short8*)&p_[32 * 64 + sl_];                     \
    }                                                                    \
  } while (0)

#define LDB(QN)                                                          \
  do {                                                                   \
    const u16* p_ = &smB[bi * 16384 + ((wc * 64 + (QN) * 32 + c5) << 6)]; \
    _Pragma("unroll") for (int s = 0; s < 4; ++s)                        \
      bf[QN][s] = *(const short8*)&p_[(((s << 1) | hi) ^ (c5 & 7)) << 3]; \
  } while (0)

#define MFMA_Q(QM, QN)                                                             \
  __builtin_amdgcn_s_setprio(1);                                                   \
  _Pragma("unroll") for (int s = 0; s < 4; ++s) {                                  \
    acc[(QM) * 2][(QN)] = __builtin_amdgcn_mfma_f32_32x32x16_bf16(                 \
        af[0][s], bf[QN][s], acc[(QM) * 2][(QN)], 0, 0, 0);                        \
    acc[(QM) * 2 + 1][(QN)] = __builtin_amdgcn_mfma_f32_32x32x16_bf16(             \
        af[1][s], bf[QN][s], acc[(QM) * 2 + 1][(QN)], 0, 0, 0);                    \
  }                                                                                \
  __builtin_amdgcn_s_setprio(0);

#define WAIT_LGKM                                         \
  asm volatile("s_waitcnt lgkmcnt(0)" ::: "memory");      \
  __builtin_amdgcn_sched_barrier(0);

template <bool OUTF32>
__global__ __launch_bounds__(512, 2) void gemm8p(
    const u16* __restrict__ A, const u16* __restrict__ B,
    const float* __restrict__ bias, void* __restrict__ Cout,
    int M, int N, int K, float oscale) {
  __shared__ u16 smA[2 * 16384];  // [buf][256 rows][64], 128B rows, 8x16B swizzled slots
  __shared__ u16 smB[2 * 16384];
  const int tid = threadIdx.x;
  const int w = tid >> 6, l = tid & 63;
  const int c5 = l & 31, hi = l >> 5;
  const int wr = w >> 2, wc = w & 3;

  // XCD-aware swizzle (nwg % 8 == 0 for all our launches)
  int flat = blockIdx.x + (int)gridDim.x * (int)blockIdx.y;
  const int nwg = (int)(gridDim.x * gridDim.y);
  flat = (flat & 7) * (nwg >> 3) + (flat >> 3);
  const int m0 = (flat / (int)gridDim.x) * 256, n0 = (flat % (int)gridDim.x) * 256;

  const int NSTEP = K / 64;
  f32x16 acc[4][2] = {};

  // staging: wave w, load j covers rows half*128 + (w*2+j)*8 + (l>>3);
  // phys slot l&7 holds global k-chunk (l&7)^(l>>3)  (pre-swizzled source)
  const int sgrp = l >> 3;
  const int scol = ((l & 7) ^ sgrp) * 8;
  const u16* As = A + (size_t)(m0 + w * 16 + sgrp) * K + scol;
  const u16* Bs = B + (size_t)(n0 + w * 16 + sgrp) * K + scol;

  // ---- prologue: tile 0 full + B0(1), A0(1); rest of tile 1 staged in t=0 ----
  STG_A(0, 0); STG_A(0, 1); STG_B(0, 0); STG_B(0, 1);
  STG_B(1, 0); STG_A(1, 0);
  asm volatile("s_waitcnt vmcnt(4)" ::: "memory");
  __builtin_amdgcn_s_barrier();

  short8 af[2][4], bf[2][4];
  for (int t = 0; t < NSTEP; ++t) {
    const int bi = t & 1;
    // ---- P0: quadrant (0,0) ----
    LDA(0); LDB(0);
    if (t + 1 < NSTEP) STG_B(t + 1, 1);
    __builtin_amdgcn_s_barrier();
    WAIT_LGKM;
    MFMA_Q(0, 0);
    __builtin_amdgcn_s_barrier();
    // ---- P1: quadrant (0,1) ----
    LDB(1);
    if (t + 1 < NSTEP) STG_A(t + 1, 1);
    __builtin_amdgcn_s_barrier();
    WAIT_LGKM;
    MFMA_Q(0, 1);
    __builtin_amdgcn_s_barrier();
    // ---- P2: quadrant (1,1) ----
    LDA(1);
    if (t + 2 < NSTEP) STG_B(t + 2, 0);
    __builtin_amdgcn_s_barrier();
    WAIT_LGKM;
    MFMA_Q(1, 1);
    __builtin_amdgcn_s_barrier();
    // ---- P3: quadrant (1,0) ----
    if (t + 2 < NSTEP) STG_A(t + 2, 0);
    __builtin_amdgcn_s_barrier();
    MFMA_Q(1, 0);
    if (t + 2 < NSTEP)
      asm volatile("s_waitcnt vmcnt(4)" ::: "memory");
    else if (t + 1 < NSTEP)
      asm volatile("s_waitcnt vmcnt(0)" ::: "memory");
    __builtin_amdgcn_s_barrier();
  }

  // epilogue: row = m0+wr*128+mf*32+(r&3)+8*(r>>2)+4*hi, col = n0+wc*64+nf*32+c5
#pragma unroll
  for (int nf = 0; nf < 2; ++nf) {
    const int col = n0 + wc * 64 + nf * 32 + c5;
    const float bv = bias[col];
#pragma unroll
    for (int mf = 0; mf < 4; ++mf) {
#pragma unroll
      for (int r = 0; r < 16; ++r) {
        const int row = m0 + wr * 128 + mf * 32 + (r & 3) + 8 * (r >> 2) + 4 * hi;
        const float v = (acc[mf][nf][r] + bv) * oscale;
        if (OUTF32)
          ((float*)Cout)[(size_t)row * N + col] = v;
        else
          ((u16*)Cout)[(size_t)row * N + col] = f2bf(v);
      }
    }
  }
}

// Flash attention: 8 waves x 32 q = 256 q/block, KV tiles of 64, 32x32x16 MFMA,
// swapped QK^T (S^T = mfma(K,Q)) -> in-register softmax (permlane32_swap),
// P->A-frag via cvt_pk_bf16 + permlane32_swap (no P LDS), double-buffered K/V.
__global__ __launch_bounds__(512, 2) void attn(
    const u16* __restrict__ Q, const u16* __restrict__ K,
    const u16* __restrict__ V, u16* __restrict__ O) {
  __shared__ u16 smK[2 * 8192];
  __shared__ u16 smV[2 * 9216];
  __shared__ float alScr[8 * 32];

  const int tid = threadIdx.x;
  const int w = tid >> 6, l = tid & 63;
  const int c5 = l & 31, hi = l >> 5;

  int flat = blockIdx.x + ((int)blockIdx.y << 3) + ((int)blockIdx.z << 7);
  flat = (flat & 7) * 64 + (flat >> 3);
  const int qt = flat & 7, h = (flat >> 3) & 15, b = flat >> 7;

  const int q0 = qt * 256 + w * 32;
  const size_t rowb = (size_t)b * SQ;
  const int hoff = h * DKH;

  short8 qf[8];
#pragma unroll
  for (int ds = 0; ds < 8; ++ds)
    qf[ds] = *(const short8*)&Q[(rowb + q0 + c5) * DM + hoff + ds * 16 + hi * 8];

  f32x16 o[4] = {};
  float mrow = -1e30f, lsum = 0.f;

  const int vdg = tid >> 5;
  const int kvp = (tid & 31) * 2;
  u16x8 va, vb;

  {
    const u16* vp = &V[(rowb + kvp) * DM + hoff + vdg * 8];
    va = *(const u16x8*)vp;
    vb = *(const u16x8*)(vp + DM);
#pragma unroll
    for (int uu = 0; uu < 2; ++uu) {
      const int u = w * 2 + uu;
      const int row = u * 4 + (l >> 4);
      const int col16 = (l & 15) ^ (row & 15);
      gload16(&K[(rowb + row) * DM + hoff + col16 * 8], &smK[u * 512]);
    }
#pragma unroll
    for (int i = 0; i < 8; ++i) {
      const int d = vdg * 8 + i;
      *(u32*)&smV[d * 72 + kvp] = (u32)va[i] | ((u32)vb[i] << 16);
    }
  }
  __syncthreads();

  int buf = 0;
  for (int t = 0; t < NT; ++t) {
    const int nb = buf ^ 1;
    if (t + 1 < NT) {
      const size_t kvr = rowb + (size_t)(t + 1) * KT;
      const u16* vp = &V[(kvr + kvp) * DM + hoff + vdg * 8];
      va = *(const u16x8*)vp;
      vb = *(const u16x8*)(vp + DM);
#pragma unroll
      for (int uu = 0; uu < 2; ++uu) {
        const int u = w * 2 + uu;
        const int row = u * 4 + (l >> 4);
        const int col16 = (l & 15) ^ (row & 15);
        gload16(&K[(kvr + row) * DM + hoff + col16 * 8], &smK[nb * 8192 + u * 512]);
      }
    }

    f32x16 s[2] = {};
    __builtin_amdgcn_s_setprio(1);
#pragma unroll
    for (int ni = 0; ni < 2; ++ni) {
      const int row = ni * 32 + c5;
#pragma unroll
      for (int ds = 0; ds < 8; ++ds) {
        const short8 kf = *(const short8*)&smK[buf * 8192 + row * 128 + (((ds << 1) | hi) ^ (row & 15)) * 8];
        s[ni] = __builtin_amdgcn_mfma_f32_32x32x16_bf16(kf, qf[ds], s[ni], 0, 0, 0);
      }
    }
    __builtin_amdgcn_s_setprio(0);

    float mx = s[0][0];
#pragma unroll
    for (int ni = 0; ni < 2; ++ni)
#pragma unroll
      for (int i = 0; i < 16; ++i)
        mx = fmaxf(mx, s[ni][i]);
    i32x2 sw = __builtin_amdgcn_permlane32_swap(__float_as_int(mx), __float_as_int(mx), false, false);
    const float gmax = fmaxf(__int_as_float(sw.x), __int_as_float(sw.y));

    if (__any(gmax > mrow + 10.0f)) {
      const float mn = fmaxf(mrow, gmax);
      const float al = exp2f(mrow - mn);
      mrow = mn;
      lsum *= al;
      alScr[w * 32 + c5] = al;
#pragma unroll
      for (int r = 0; r < 16; ++r) {
        const float av = alScr[w * 32 + (r & 3) + 8 * (r >> 2) + 4 * hi];
#pragma unroll
        for (int dg = 0; dg < 4; ++dg) o[dg][r] *= av;
      }
    }

    float ps0 = 0.f, ps1 = 0.f;
#pragma unroll
    for (int i = 0; i < 16; ++i) {
      const float p0 = exp2f(s[0][i] - mrow);
      const float p1 = exp2f(s[1][i] - mrow);
      s[0][i] = p0; s[1][i] = p1;
      ps0 += p0; ps1 += p1;
    }
    lsum += ps0 + ps1;

    __builtin_amdgcn_s_setprio(1);
#pragma unroll
    for (int ks = 0; ks < 4; ++ks) {
      const int b0 = (ks & 1) * 8;
      const int ni = ks >> 1;
      const u32 A0 = cvtpk(s[ni][b0 + 0], s[ni][b0 + 1]);
      const u32 A1 = cvtpk(s[ni][b0 + 4], s[ni][b0 + 5]);
      const u32 B0 = cvtpk(s[ni][b0 + 2], s[ni][b0 + 3]);
      const u32 B1 = cvtpk(s[ni][b0 + 6], s[ni][b0 + 7]);
      const i32x2 r0 = __builtin_amdgcn_permlane32_swap((int)A0, (int)A1, false, false);
      const i32x2 r1 = __builtin_amdgcn_permlane32_swap((int)B0, (int)B1, false, false);
      u32x4 paw;
      paw.x = (u32)r0.x; paw.y = (u32)r1.x; paw.z = (u32)r0.y; paw.w = (u32)r1.y;
      const short8 pa = *(const short8*)&paw;
#pragma unroll
      for (int dg = 0; dg < 4; ++dg) {
        const int rowd = dg * 32 + c5;
        const short8 vf = *(const short8*)&smV[buf * 9216 + rowd * 72 + ks * 16 + hi * 8];
        o[dg] = __builtin_amdgcn_mfma_f32_32x32x16_bf16(pa, vf, o[dg], 0, 0, 0);
      }
    }
    __builtin_amdgcn_s_setprio(0);

    if (t + 1 < NT) {
#pragma unroll
      for (int i = 0; i < 8; ++i) {
        const int d = vdg * 8 + i;
        *(u32*)&smV[nb * 9216 + d * 72 + kvp] = (u32)va[i] | ((u32)vb[i] << 16);
      }
    }
    __syncthreads();
    buf = nb;
  }

  {
    const i32x2 sl = __builtin_amdgcn_permlane32_swap(__float_as_int(lsum), __float_as_int(lsum), false, false);
    const float tot = __int_as_float(sl.x) + __int_as_float(sl.y);
    alScr[w * 32 + c5] = 1.0f / tot;
  }
#pragma unroll
  for (int r = 0; r < 16; ++r) {
    const int qloc = (r & 3) + 8 * (r >> 2) + 4 * hi;
    const float inv = alScr[w * 32 + qloc];
    const size_t orow = (rowb + q0 + qloc) * DM + hoff;
#pragma unroll
    for (int dg = 0; dg < 4; ++dg)
      O[orow + dg * 32 + c5] = f2bf(o[dg][r] * inv);
  }
}

extern "C" void kernel_launch(void* const* d_in, const int* in_sizes, int n_in,
                              void* d_out, int out_size, void* d_ws, size_t ws_size,
                              hipStream_t stream) {
  const float* x    = (const float*)d_in[0];
  const float* wq_w = (const float*)d_in[1];
  const float* wq_b = (const float*)d_in[2];
  const float* wk_w = (const float*)d_in[3];
  const float* wk_b = (const float*)d_in[4];
  const float* wv_w = (const float*)d_in[5];
  const float* wv_b = (const float*)d_in[6];
  const float* wo_w = (const float*)d_in[7];
  const float* wo_b = (const float*)d_in[8];
  float* out = (float*)d_out;

  u16* p = (u16*)d_ws;
  u16* xb  = p; p += (size_t)NB * SQ * DM;
  u16* wqb = p; p += (size_t)DM * DM;
  u16* wkb = p; p += (size_t)DM * DM;
  u16* wvb = p; p += (size_t)DM * DM;
  u16* wob = p; p += (size_t)DM * DM;
  u16* Qb  = p; p += (size_t)NB * SQ * DM;
  u16* Kb  = p; p += (size_t)NB * SQ * DM;
  u16* Vb  = p; p += (size_t)NB * SQ * DM;
  u16* ctx = xb;  // reuse: x no longer needed after V projection

  const int nx = NB * SQ * DM;
  cvt_bf16<<<dim3(nx / 1024), dim3(256), 0, stream>>>(x, xb, nx);
  cvt_w4<<<dim3(DM * DM / 1024, 4), dim3(256), 0, stream>>>(wq_w, wk_w, wv_w, wo_w, wqb);

  const float sc2 = 0.08838834764831845f * 1.4426950408889634f;  // 1/sqrt(128)*log2(e)
  dim3 gg(DM / 256, (NB * SQ) / 256);
  gemm8p<false><<<gg, dim3(512), 0, stream>>>(xb, wqb, wq_b, Qb, NB * SQ, DM, DM, sc2);
  gemm8p<false><<<gg, dim3(512), 0, stream>>>(xb, wkb, wk_b, Kb, NB * SQ, DM, DM, 1.0f);
  gemm8p<false><<<gg, dim3(512), 0, stream>>>(xb, wvb, wv_b, Vb, NB * SQ, DM, DM, 1.0f);

  attn<<<dim3(SQ / 256, NH, NB), dim3(512), 0, stream>>>(Qb, Kb, Vb, ctx);

  gemm8p<true><<<gg, dim3(512), 0, stream>>>(ctx, wob, wo_b, out, NB * SQ, DM, DM, 1.0f);
}

// Round 6
// 549.997 us; speedup vs baseline: 1.7844x; 1.0247x over previous
//
#include <hip/hip_runtime.h>
#include <hip/hip_bf16.h>
#include <math.h>

typedef __attribute__((ext_vector_type(8))) short short8;
typedef __attribute__((ext_vector_type(4))) float f32x4;
typedef __attribute__((ext_vector_type(16))) float f32x16;
typedef __attribute__((ext_vector_type(4))) unsigned short u16x4;
typedef __attribute__((ext_vector_type(8))) unsigned short u16x8;
typedef __attribute__((ext_vector_type(4))) unsigned int u32x4;
typedef __attribute__((ext_vector_type(2))) int i32x2;
typedef unsigned short u16;
typedef unsigned int u32;

#define DM 2048
#define SQ 2048
#define NB 4
#define NH 16
#define DKH 128
#define KT 64
#define NT (SQ / KT)
#define LD3 (3 * DM)
#define QSCALE (0.08838834764831845f * 1.4426950408889634f)

__device__ __forceinline__ u16 f2bf(float f) {
  unsigned u = __float_as_uint(f);
  u += 0x7fffu + ((u >> 16) & 1u);
  return (u16)(u >> 16);
}

__device__ __forceinline__ u32 cvtpk(float lo, float hi) {
  u32 r;
  asm("v_cvt_pk_bf16_f32 %0, %1, %2" : "=v"(r) : "v"(lo), "v"(hi));
  return r;
}

__device__ __forceinline__ void gload16(const u16* g, u16* lds) {
  __builtin_amdgcn_global_load_lds(
      (const __attribute__((address_space(1))) unsigned int*)g,
      (__attribute__((address_space(3))) unsigned int*)lds, 16, 0, 0);
}

__global__ void cvt_bf16(const float* __restrict__ in, u16* __restrict__ out, int n) {
  int i = (blockIdx.x * blockDim.x + threadIdx.x) * 4;
  if (i >= n) return;
  float4 v = *(const float4*)(in + i);
  u16x4 o;
  o.x = f2bf(v.x); o.y = f2bf(v.y); o.z = f2bf(v.z); o.w = f2bf(v.w);
  *(u16x4*)(out + i) = o;
}

// 4 weight matrices -> contiguous bf16 dst (blockIdx.y selects source)
__global__ void cvt_w4(const float* __restrict__ w0, const float* __restrict__ w1,
                       const float* __restrict__ w2, const float* __restrict__ w3,
                       u16* __restrict__ dst) {
  const int sel = blockIdx.y;
  const float* src;
  switch (sel) {
    case 0: src = w0; break;
    case 1: src = w1; break;
    case 2: src = w2; break;
    default: src = w3; break;
  }
  const int i = (blockIdx.x * blockDim.x + threadIdx.x) * 4;
  float4 v = *(const float4*)(src + i);
  u16x4 o;
  o.x = f2bf(v.x); o.y = f2bf(v.y); o.z = f2bf(v.z); o.w = f2bf(v.w);
  *(u16x4*)(dst + (size_t)sel * DM * DM + i) = o;
}

// ---------------- 256x256 8-phase pipelined GEMM ----------------
// MODE 0: fused QKV — C bf16 [M][N=6144]; bias/scale selected per 2048-col segment
//         (seg0 = wq_b, scaled by QSCALE; seg1 = wk_b; seg2 = wv_b).
// MODE 1: single — C f32 [M][N], bias = bq.

#define STG_A(T, HALF)                                                \
  do {                                                                \
    u16* d_ = &smA[((T) & 1) * 16384 + (((HALF) * 128 + w * 16) << 6)]; \
    const u16* s_ = As + (size_t)((HALF) * 128) * K + (size_t)(T) * 64; \
    gload16(s_, d_);                                                  \
    gload16(s_ + (size_t)8 * K, d_ + 8 * 64);                         \
  } while (0)

#define STG_B(T, HALF)                                                \
  do {                                                                \
    u16* d_ = &smB[((T) & 1) * 16384 + (((HALF) * 128 + w * 16) << 6)]; \
    const u16* s_ = Bs + (size_t)((HALF) * 128) * K + (size_t)(T) * 64; \
    gload16(s_, d_);                                                  \
    gload16(s_ + (size_t)8 * K, d_ + 8 * 64);                         \
  } while (0)

#define LDA(QM)                                                          \
  do {                                                                   \
    const u16* p_ = &smA[bi * 16384 + ((wr * 128 + (QM) * 64 + c5) << 6)]; \
    _Pragma("unroll") for (int s = 0; s < 4; ++s) {                      \
      const int sl_ = (((s << 1) | hi) ^ (c5 & 7)) << 3;                 \
      af[0][s] = *(const short8*)&p_[sl_];                               \
      af[1][s] = *(const short8*)&p_[32 * 64 + sl_];                     \
    }                                                                    \
  } while (0)

#define LDB(QN)                                                          \
  do {                                                                   \
    const u16* p_ = &smB[bi * 16384 + ((wc * 64 + (QN) * 32 + c5) << 6)]; \
    _Pragma("unroll") for (int s = 0; s < 4; ++s)                        \
      bf[QN][s] = *(const short8*)&p_[(((s << 1) | hi) ^ (c5 & 7)) << 3]; \
  } while (0)

#define MFMA_Q(QM, QN)                                                             \
  __builtin_amdgcn_s_setprio(1);                                                   \
  _Pragma("unroll") for (int s = 0; s < 4; ++s) {                                  \
    acc[(QM) * 2][(QN)] = __builtin_amdgcn_mfma_f32_32x32x16_bf16(                 \
        af[0][s], bf[QN][s], acc[(QM) * 2][(QN)], 0, 0, 0);                        \
    acc[(QM) * 2 + 1][(QN)] = __builtin_amdgcn_mfma_f32_32x32x16_bf16(             \
        af[1][s], bf[QN][s], acc[(QM) * 2 + 1][(QN)], 0, 0, 0);                    \
  }                                                                                \
  __builtin_amdgcn_s_setprio(0);

#define WAIT_LGKM                                         \
  asm volatile("s_waitcnt lgkmcnt(0)" ::: "memory");      \
  __builtin_amdgcn_sched_barrier(0);

template <int MODE>
__global__ __launch_bounds__(512, 2) void gemm8p(
    const u16* __restrict__ A, const u16* __restrict__ B,
    const float* __restrict__ bq, const float* __restrict__ bk,
    const float* __restrict__ bvp, void* __restrict__ Cout,
    int M, int N, int K) {
  __shared__ u16 smA[2 * 16384];  // [buf][256 rows][64], 128B rows, 8x16B swizzled slots
  __shared__ u16 smB[2 * 16384];
  const int tid = threadIdx.x;
  const int w = tid >> 6, l = tid & 63;
  const int c5 = l & 31, hi = l >> 5;
  const int wr = w >> 2, wc = w & 3;

  // XCD-aware swizzle (nwg % 8 == 0 for all our launches)
  int flat = blockIdx.x + (int)gridDim.x * (int)blockIdx.y;
  const int nwg = (int)(gridDim.x * gridDim.y);
  flat = (flat & 7) * (nwg >> 3) + (flat >> 3);
  const int m0 = (flat / (int)gridDim.x) * 256, n0 = (flat % (int)gridDim.x) * 256;

  const int NSTEP = K / 64;
  f32x16 acc[4][2] = {};

  const int sgrp = l >> 3;
  const int scol = ((l & 7) ^ sgrp) * 8;
  const u16* As = A + (size_t)(m0 + w * 16 + sgrp) * K + scol;
  const u16* Bs = B + (size_t)(n0 + w * 16 + sgrp) * K + scol;

  STG_A(0, 0); STG_A(0, 1); STG_B(0, 0); STG_B(0, 1);
  STG_B(1, 0); STG_A(1, 0);
  asm volatile("s_waitcnt vmcnt(4)" ::: "memory");
  __builtin_amdgcn_s_barrier();

  short8 af[2][4], bf[2][4];
  for (int t = 0; t < NSTEP; ++t) {
    const int bi = t & 1;
    LDA(0); LDB(0);
    if (t + 1 < NSTEP) STG_B(t + 1, 1);
    __builtin_amdgcn_s_barrier();
    WAIT_LGKM;
    MFMA_Q(0, 0);
    __builtin_amdgcn_s_barrier();
    LDB(1);
    if (t + 1 < NSTEP) STG_A(t + 1, 1);
    __builtin_amdgcn_s_barrier();
    WAIT_LGKM;
    MFMA_Q(0, 1);
    __builtin_amdgcn_s_barrier();
    LDA(1);
    if (t + 2 < NSTEP) STG_B(t + 2, 0);
    __builtin_amdgcn_s_barrier();
    WAIT_LGKM;
    MFMA_Q(1, 1);
    __builtin_amdgcn_s_barrier();
    if (t + 2 < NSTEP) STG_A(t + 2, 0);
    __builtin_amdgcn_s_barrier();
    MFMA_Q(1, 0);
    if (t + 2 < NSTEP)
      asm volatile("s_waitcnt vmcnt(4)" ::: "memory");
    else if (t + 1 < NSTEP)
      asm volatile("s_waitcnt vmcnt(0)" ::: "memory");
    __builtin_amdgcn_s_barrier();
  }

#pragma unroll
  for (int nf = 0; nf < 2; ++nf) {
    const int col = n0 + wc * 64 + nf * 32 + c5;
    float bval, os;
    if (MODE == 0) {
      const int seg = col >> 11;
      const float* bp = seg == 0 ? bq : (seg == 1 ? bk : bvp);
      bval = bp[col & (DM - 1)];
      os = (seg == 0) ? QSCALE : 1.0f;
    } else {
      bval = bq[col];
      os = 1.0f;
    }
#pragma unroll
    for (int mf = 0; mf < 4; ++mf) {
#pragma unroll
      for (int r = 0; r < 16; ++r) {
        const int row = m0 + wr * 128 + mf * 32 + (r & 3) + 8 * (r >> 2) + 4 * hi;
        const float v = (acc[mf][nf][r] + bval) * os;
        if (MODE == 1)
          ((float*)Cout)[(size_t)row * N + col] = v;
        else
          ((u16*)Cout)[(size_t)row * N + col] = f2bf(v);
      }
    }
  }
}

// Flash attention: 8 waves x 32 q = 256 q/block, KV tiles of 64, 32x32x16 MFMA,
// swapped QK^T -> in-register softmax, P via cvt_pk + permlane32_swap.
// QKV fused layout: row stride 3*DM; Q at col 0, K at DM, V at 2*DM.
// K double-buffered (gload_lds); V single-buffered write-late (2 barriers/tile)
// -> LDS 52 KB -> 2 blocks/CU resident.
__global__ __launch_bounds__(512, 2) void attn(
    const u16* __restrict__ QKV, u16* __restrict__ O) {
  __shared__ u16 smK[2 * 8192];   // [buf][kv 64][256B rows, 16x16B slots, ^row&15]
  __shared__ u16 smV[9216];       // [d 128][144B rows: 64 kv + 8 pad]
  __shared__ float alScr[8 * 32];

  const u16* Qp = QKV;
  const u16* Kp = QKV + DM;
  const u16* Vp = QKV + 2 * DM;

  const int tid = threadIdx.x;
  const int w = tid >> 6, l = tid & 63;
  const int c5 = l & 31, hi = l >> 5;

  int flat = blockIdx.x + ((int)blockIdx.y << 3) + ((int)blockIdx.z << 7);
  flat = (flat & 7) * 64 + (flat >> 3);
  const int qt = flat & 7, h = (flat >> 3) & 15, b = flat >> 7;

  const int q0 = qt * 256 + w * 32;
  const size_t rowb = (size_t)b * SQ;
  const int hoff = h * DKH;

  short8 qf[8];
#pragma unroll
  for (int ds = 0; ds < 8; ++ds)
    qf[ds] = *(const short8*)&Qp[(rowb + q0 + c5) * LD3 + hoff + ds * 16 + hi * 8];

  f32x16 o[4] = {};
  float mrow = -1e30f, lsum = 0.f;

  const int vdg = tid >> 5;
  const int kvp = (tid & 31) * 2;
  u16x8 va, vb;

  // ---- prologue: K0 -> smK[0], V0 -> regs -> smV ----
  {
#pragma unroll
    for (int uu = 0; uu < 2; ++uu) {
      const int u = w * 2 + uu;
      const int row = u * 4 + (l >> 4);
      const int col16 = (l & 15) ^ (row & 15);
      gload16(&Kp[(rowb + row) * LD3 + hoff + col16 * 8], &smK[u * 512]);
    }
    const u16* vp = &Vp[(rowb + kvp) * LD3 + hoff + vdg * 8];
    va = *(const u16x8*)vp;
    vb = *(const u16x8*)(vp + LD3);
#pragma unroll
    for (int i = 0; i < 8; ++i) {
      const int d = vdg * 8 + i;
      *(u32*)&smV[d * 72 + kvp] = (u32)va[i] | ((u32)vb[i] << 16);
    }
  }
  __syncthreads();

  int buf = 0;
  for (int t = 0; t < NT; ++t) {
    const int nb = buf ^ 1;
    if (t + 1 < NT) {
      const size_t kvr = rowb + (size_t)(t + 1) * KT;
#pragma unroll
      for (int uu = 0; uu < 2; ++uu) {
        const int u = w * 2 + uu;
        const int row = u * 4 + (l >> 4);
        const int col16 = (l & 15) ^ (row & 15);
        gload16(&Kp[(kvr + row) * LD3 + hoff + col16 * 8], &smK[nb * 8192 + u * 512]);
      }
      const u16* vp = &Vp[(kvr + kvp) * LD3 + hoff + vdg * 8];
      va = *(const u16x8*)vp;
      vb = *(const u16x8*)(vp + LD3);
    }

    f32x16 s[2] = {};
    __builtin_amdgcn_s_setprio(1);
#pragma unroll
    for (int ni = 0; ni < 2; ++ni) {
      const int row = ni * 32 + c5;
#pragma unroll
      for (int ds = 0; ds < 8; ++ds) {
        const short8 kf = *(const short8*)&smK[buf * 8192 + row * 128 + (((ds << 1) | hi) ^ (row & 15)) * 8];
        s[ni] = __builtin_amdgcn_mfma_f32_32x32x16_bf16(kf, qf[ds], s[ni], 0, 0, 0);
      }
    }
    __builtin_amdgcn_s_setprio(0);

    float mx = s[0][0];
#pragma unroll
    for (int ni = 0; ni < 2; ++ni)
#pragma unroll
      for (int i = 0; i < 16; ++i)
        mx = fmaxf(mx, s[ni][i]);
    i32x2 sw = __builtin_amdgcn_permlane32_swap(__float_as_int(mx), __float_as_int(mx), false, false);
    const float gmax = fmaxf(__int_as_float(sw.x), __int_as_float(sw.y));

    if (__any(gmax > mrow + 10.0f)) {
      const float mn = fmaxf(mrow, gmax);
      const float al = exp2f(mrow - mn);
      mrow = mn;
      lsum *= al;
      alScr[w * 32 + c5] = al;
#pragma unroll
      for (int r = 0; r < 16; ++r) {
        const float av = alScr[w * 32 + (r & 3) + 8 * (r >> 2) + 4 * hi];
#pragma unroll
        for (int dg = 0; dg < 4; ++dg) o[dg][r] *= av;
      }
    }

    float ps0 = 0.f, ps1 = 0.f;
#pragma unroll
    for (int i = 0; i < 16; ++i) {
      const float p0 = exp2f(s[0][i] - mrow);
      const float p1 = exp2f(s[1][i] - mrow);
      s[0][i] = p0; s[1][i] = p1;
      ps0 += p0; ps1 += p1;
    }
    lsum += ps0 + ps1;

    __builtin_amdgcn_s_setprio(1);
#pragma unroll
    for (int ks = 0; ks < 4; ++ks) {
      const int b0 = (ks & 1) * 8;
      const int ni = ks >> 1;
      const u32 A0 = cvtpk(s[ni][b0 + 0], s[ni][b0 + 1]);
      const u32 A1 = cvtpk(s[ni][b0 + 4], s[ni][b0 + 5]);
      const u32 B0 = cvtpk(s[ni][b0 + 2], s[ni][b0 + 3]);
      const u32 B1 = cvtpk(s[ni][b0 + 6], s[ni][b0 + 7]);
      const i32x2 r0 = __builtin_amdgcn_permlane32_swap((int)A0, (int)A1, false, false);
      const i32x2 r1 = __builtin_amdgcn_permlane32_swap((int)B0, (int)B1, false, false);
      u32x4 paw;
      paw.x = (u32)r0.x; paw.y = (u32)r1.x; paw.z = (u32)r0.y; paw.w = (u32)r1.y;
      const short8 pa = *(const short8*)&paw;
#pragma unroll
      for (int dg = 0; dg < 4; ++dg) {
        const int rowd = dg * 32 + c5;
        const short8 vf = *(const short8*)&smV[rowd * 72 + ks * 16 + hi * 8];
        o[dg] = __builtin_amdgcn_mfma_f32_32x32x16_bf16(pa, vf, o[dg], 0, 0, 0);
      }
    }
    __builtin_amdgcn_s_setprio(0);

    // barrier #1: all waves done with PV(t); drains vmcnt (K(t+1) staged, V regs ready)
    __syncthreads();
    if (t + 1 < NT) {
#pragma unroll
      for (int i = 0; i < 8; ++i) {
        const int d = vdg * 8 + i;
        *(u32*)&smV[d * 72 + kvp] = (u32)va[i] | ((u32)vb[i] << 16);
      }
      // barrier #2: V(t+1) visible to all waves before any PV(t+1)
      __syncthreads();
    }
    buf = nb;
  }

  {
    const i32x2 sl = __builtin_amdgcn_permlane32_swap(__float_as_int(lsum), __float_as_int(lsum), false, false);
    const float tot = __int_as_float(sl.x) + __int_as_float(sl.y);
    alScr[w * 32 + c5] = 1.0f / tot;
  }
#pragma unroll
  for (int r = 0; r < 16; ++r) {
    const int qloc = (r & 3) + 8 * (r >> 2) + 4 * hi;
    const float inv = alScr[w * 32 + qloc];
    const size_t orow = (rowb + q0 + qloc) * DM + hoff;
#pragma unroll
    for (int dg = 0; dg < 4; ++dg)
      O[orow + dg * 32 + c5] = f2bf(o[dg][r] * inv);
  }
}

extern "C" void kernel_launch(void* const* d_in, const int* in_sizes, int n_in,
                              void* d_out, int out_size, void* d_ws, size_t ws_size,
                              hipStream_t stream) {
  const float* x    = (const float*)d_in[0];
  const float* wq_w = (const float*)d_in[1];
  const float* wq_b = (const float*)d_in[2];
  const float* wk_w = (const float*)d_in[3];
  const float* wk_b = (const float*)d_in[4];
  const float* wv_w = (const float*)d_in[5];
  const float* wv_b = (const float*)d_in[6];
  const float* wo_w = (const float*)d_in[7];
  const float* wo_b = (const float*)d_in[8];
  float* out = (float*)d_out;

  u16* p = (u16*)d_ws;
  u16* xb  = p; p += (size_t)NB * SQ * DM;       // x (bf16), later reused as ctx
  u16* wqb = p; p += (size_t)3 * DM * DM;        // wq|wk|wv stacked (fused B)
  u16* wob = p; p += (size_t)DM * DM;
  u16* QKV = p; p += (size_t)NB * SQ * 3 * DM;   // fused [8192][6144] output
  u16* ctx = xb;

  const int nx = NB * SQ * DM;
  cvt_bf16<<<dim3(nx / 1024), dim3(256), 0, stream>>>(x, xb, nx);
  cvt_w4<<<dim3(DM * DM / 1024, 4), dim3(256), 0, stream>>>(wq_w, wk_w, wv_w, wo_w, wqb);

  // fused QKV projection: [8192][2048] @ [6144][2048]^T -> [8192][6144]
  dim3 gg3(3 * DM / 256, (NB * SQ) / 256);
  gemm8p<0><<<gg3, dim3(512), 0, stream>>>(xb, wqb, wq_b, wk_b, wv_b, QKV,
                                           NB * SQ, 3 * DM, DM);

  attn<<<dim3(SQ / 256, NH, NB), dim3(512), 0, stream>>>(QKV, ctx);

  dim3 ggo(DM / 256, (NB * SQ) / 256);
  gemm8p<1><<<ggo, dim3(512), 0, stream>>>(ctx, wob, wo_b, nullptr, nullptr, out,
                                           NB * SQ, DM, DM);
}